// Round 10
// baseline (553.182 us; speedup 1.0000x reference)
//
#include <hip/hip_runtime.h>
#include <cstdint>
#include <cstddef>

typedef __bf16 bf16_t;
typedef bf16_t bf16x8 __attribute__((ext_vector_type(8)));
typedef bf16_t bf16x4 __attribute__((ext_vector_type(4)));
typedef float f32x4 __attribute__((ext_vector_type(4)));

#define B_SZ    4
#define LSEQ    2048
#define DMODEL  1024
#define EDIM    2048
#define ZDIM    4419
#define ZPAD    4608
#define ROWS    (B_SZ*LSEQ)     /* 8192 */
#define EPSV    1e-5f

/* padded leading dims */
#define LDU     1088
#define LDG     2112

#define SCHUNK  128
#define SCLEN   (LSEQ/SCHUNK)   /* 16 */
#define RCH     128
#define RCLEN   (LSEQ/RCH)      /* 16 */

// ---------------- helpers ----------------
__device__ __forceinline__ float softplus_f(float x){
  return fmaxf(x, 0.f) + log1pf(expf(-fabsf(x)));
}
__device__ __forceinline__ float sigmoid_f(float x){ return 1.f/(1.f+expf(-x)); }
__device__ __forceinline__ float silu_f(float x){ return x/(1.f+expf(-x)); }

__device__ __forceinline__ void gload_lds16(const void* g, void* l){
  __builtin_amdgcn_global_load_lds(
      (const __attribute__((address_space(1))) void*)g,
      (__attribute__((address_space(3))) void*)l, 16, 0, 0);
}

__device__ __forceinline__ float blockReduce128(float v, float* red, int t){
  red[t] = v; __syncthreads();
  #pragma unroll
  for (int off = 64; off > 0; off >>= 1){
    if (t < off) red[t] += red[t+off];
    __syncthreads();
  }
  float r = red[0];
  __syncthreads();
  return r;
}

// ---------------- kernel 0: vectorized casts + zero accumulators -----------
__global__ __launch_bounds__(256) void prep_kernel(
    const float4* __restrict__ u4, const float4* __restrict__ win4,
    const float4* __restrict__ wout4,
    bf16_t* __restrict__ ubf, bf16_t* __restrict__ winbf, bf16_t* __restrict__ woutbf,
    float* __restrict__ Asum, float* __restrict__ xraw)
{
  size_t i = (size_t)blockIdx.x*256 + threadIdx.x;
  if (i == 0) Asum[0] = 0.f;
  if (i < ROWS) xraw[i] = 0.f;
  const size_t NU4 = (size_t)ROWS*DMODEL/4;
  const size_t NW4 = (size_t)ZPAD*DMODEL/4;
  const size_t NO4 = (size_t)DMODEL*EDIM/4;
  if (i < NU4){
    float4 v = u4[i];
    size_t e = i*4, row = e>>10, col = e&1023;
    bf16x4 o = { (bf16_t)v.x, (bf16_t)v.y, (bf16_t)v.z, (bf16_t)v.w };
    *(bf16x4*)&ubf[row*LDU + col] = o;
    return;
  }
  i -= NU4;
  if (i < NW4){
    size_t e = i*4, row = e>>10, col = e&1023;
    bf16x4 o;
    if (row < (size_t)ZDIM){
      float4 v = win4[i];
      o = bf16x4{ (bf16_t)v.x, (bf16_t)v.y, (bf16_t)v.z, (bf16_t)v.w };
    } else {
      o = bf16x4{ (bf16_t)0.f, (bf16_t)0.f, (bf16_t)0.f, (bf16_t)0.f };
    }
    *(bf16x4*)&winbf[row*LDU + col] = o;
    return;
  }
  i -= NW4;
  if (i < NO4){
    float4 v = wout4[i];
    size_t e = i*4, row = e>>11, col = e&2047;
    bf16x4 o = { (bf16_t)v.x, (bf16_t)v.y, (bf16_t)v.z, (bf16_t)v.w };
    *(bf16x4*)&woutbf[row*LDG + col] = o;
  }
}

// -------- A-direct GEMM: A global->VGPR, B via 64KB LDS K-chunks ----------
// C = A[M][LDA_] @ W[N][LDW_]^T, bf16 row-major, K = NCH*256 per block.
// 256 thr = 4 waves (2x2): per-wave 128x64 output, acc[8][4] (128 VGPR).
// A-fragments loaded DIRECTLY global->register (each wave's rows private;
// compiler pipelines buffer loads across the fully-unrolled 8-substep chunk
// with its own counted vmcnt — no barrier on the A path). B staged per
// K-chunk (128 rows x 256 k = 64 KB LDS, single buffer): one
// stage+vmcnt(0)+barrier drain per 8 K-steps (vs per-step before).
// B-LDS swizzle: byte ^= (row&7)<<4, source pre-swizzled (rule #21).
// 2 blocks/CU. Bijective XCD swizzle.
// MODE 0 (GEMM1): n0<2048 -> silu row-sum atomics into xraw;
//   2048..4095 -> silu -> o_g (stride LDG); 4096..4479 -> o_z fp32.
// MODE 1 (GEMM2 split-K x2): atomicAdd(o_f, acc*scale[row]).
template<int LDA_, int LDW_, int NCH, int NXT, int MODE>
__global__ __launch_bounds__(256, 2) void gemmAD_kernel(
    const bf16_t* __restrict__ A0, const bf16_t* __restrict__ W0,
    float* __restrict__ xraw, bf16_t* __restrict__ o_g, float* __restrict__ o_z,
    const float* __restrict__ scale, float* __restrict__ o_f)
{
  __shared__ __align__(16) bf16_t ldsB[32768];   // 64 KB: [128 rows][256 k]

  const int tid = threadIdx.x;
  const int wid = tid>>6, lane = tid&63;
  const int wr = wid>>1, wc = wid&1;
  const int lr = lane&15, hi = lane>>4;
  const int hv = hi*16;                 // byte offset of k-oct
  const int swz = (lr&7)<<4;            // B-read swizzle (row&7 == lr&7)

  constexpr int NWG = (MODE==0) ? NXT*(ROWS/256) : NXT*(ROWS/256)*2;
  const int id = blockIdx.x;
  const int rid = (id & 7)*(NWG/8) + (id>>3);    // bijective (NWG%8==0)
  int bx, by, kz = 0;
  if (MODE == 0){ bx = rid % NXT; by = rid / NXT; }
  else { kz = rid / (NXT*(ROWS/256)); int r2 = rid % (NXT*(ROWS/256));
         bx = r2 % NXT; by = r2 / NXT; }
  const int m0 = by*256, n0 = bx*128;

  f32x4 acc[8][4] = {};

  // ---- A: per-lane direct-load pointers (advance +256 elems per chunk) ----
  const bf16_t* pa[8];
  #pragma unroll
  for (int m = 0; m < 8; ++m)
    pa[m] = A0 + (size_t)(m0 + wr*128 + m*16 + lr)*LDA_ + (size_t)kz*1024 + hv/2;

  // ---- B: staging offsets (loop-invariant) + read row bases ----
  int gwoff[16];
  #pragma unroll
  for (int q = 0; q < 16; ++q){
    int c = q*256 + tid;
    int row = c>>5, wi = (c&31)*16;            // dest byte-within-row
    gwoff[q] = (n0+row)*LDW_ + ((wi ^ ((row&7)<<4))>>1);
  }
  const bf16_t* Wb = W0 + (size_t)kz*1024;
  int rowbase[4];
  #pragma unroll
  for (int n = 0; n < 4; ++n)
    rowbase[n] = (wc*64 + n*16 + lr)*512;      // byte base of row in ldsB

  #pragma unroll 1
  for (int c = 0; c < NCH; ++c){
    __syncthreads();                           // prev chunk fully consumed
    #pragma unroll
    for (int q = 0; q < 16; ++q)
      gload_lds16(Wb + gwoff[q], &ldsB[(q*256 + tid)*8]);
    Wb += 256;
    asm volatile("s_waitcnt vmcnt(0)" ::: "memory");
    __syncthreads();                           // B chunk visible to all

    #pragma unroll
    for (int ks = 0; ks < 8; ++ks){
      bf16x8 bfr[4];
      const int ksv = ks*64 + hv;
      #pragma unroll
      for (int n = 0; n < 4; ++n)
        bfr[n] = *(const bf16x8*)((const char*)ldsB + rowbase[n] + (ksv ^ swz));
      #pragma unroll
      for (int m = 0; m < 8; ++m){
        bf16x8 af = *(const bf16x8*)(pa[m] + ks*32);
        #pragma unroll
        for (int n = 0; n < 4; ++n)
          acc[m][n] = __builtin_amdgcn_mfma_f32_16x16x32_bf16(af, bfr[n], acc[m][n], 0,0,0);
      }
    }
    #pragma unroll
    for (int m = 0; m < 8; ++m) pa[m] += 256;
  }

  // ---- epilogue (row = m0 + wr*128 + m*16 + hi*4 + i; col = n0 + wc*64 + n*16 + lr)
  if (MODE == 0 && n0 < 2048){
    #pragma unroll
    for (int m = 0; m < 8; ++m){
      #pragma unroll
      for (int i = 0; i < 4; ++i){
        float p = 0.f;
        #pragma unroll
        for (int n = 0; n < 4; ++n) p += silu_f(acc[m][n][i]);
        p += __shfl_xor(p, 8); p += __shfl_xor(p, 4);
        p += __shfl_xor(p, 2); p += __shfl_xor(p, 1);
        if (lr == 0){
          int r = m0 + wr*128 + m*16 + (hi<<2) + i;
          atomicAdd(xraw + r, p);
        }
      }
    }
  } else if (MODE == 0){
    #pragma unroll
    for (int m = 0; m < 8; ++m){
      int rowb = m0 + wr*128 + m*16 + (hi<<2);
      #pragma unroll
      for (int n = 0; n < 4; ++n){
        int col = n0 + wc*64 + n*16 + lr;
        #pragma unroll
        for (int i = 0; i < 4; ++i){
          int r = rowb + i;
          float v = acc[m][n][i];
          if (col < 4096)      o_g[(size_t)r*LDG + (col-2048)] = (bf16_t)silu_f(v);
          else if (col < 4480) o_z[(size_t)r*384 + (col-4096)] = v;
        }
      }
    }
  } else {
    #pragma unroll
    for (int m = 0; m < 8; ++m){
      int rowb = m0 + wr*128 + m*16 + (hi<<2);
      #pragma unroll
      for (int i = 0; i < 4; ++i){
        int r = rowb + i;
        float s = scale[r];
        #pragma unroll
        for (int n = 0; n < 4; ++n){
          int col = n0 + wc*64 + n*16 + lr;
          atomicAdd(o_f + (size_t)r*DMODEL + col, acc[m][n][i]*s);
        }
      }
    }
  }
}

// ---------------- kernel 2: per-token fuse (RMS + scalars) ----------------
__global__ __launch_bounds__(128) void fuse_kernel(
    const float* __restrict__ xraw, const float* __restrict__ zs,
    const float* __restrict__ wnB, const float* __restrict__ wnC,
    const float* __restrict__ Bb, const float* __restrict__ Cb,
    const float* __restrict__ dtb, const float* __restrict__ Alog,
    float* __restrict__ Bn, float* __restrict__ Cn, float* __restrict__ dtth,
    float* __restrict__ dts, float* __restrict__ alphas, float* __restrict__ lams,
    float* __restrict__ xbar, float* Asum)
{
  __shared__ float red[128];
  int r = blockIdx.x, t = threadIdx.x;
  const float* zr = zs + (size_t)r*384;
  float bv = zr[t], cv = zr[128+t];
  float b2 = blockReduce128(bv*bv, red, t);
  float c2 = blockReduce128(cv*cv, red, t);
  float rb = rsqrtf(b2*(1.f/128.f) + EPSV);
  float rc = rsqrtf(c2*(1.f/128.f) + EPSV);
  Bn[(size_t)r*128 + t] = bv*rb*wnB[t] + Bb[t];
  Cn[(size_t)r*128 + t] = cv*rc*wnC[t] + Cb[t];

  float dt = softplus_f(zr[256] + dtb[0]);
  if (t < 64) dtth[(size_t)r*64 + t] = dt * zr[258+t];
  if (t == 0){
    float Av  = -softplus_f(zr[257] + Alog[0]);
    float lam = sigmoid_f(zr[322]);
    dts[r]    = dt;
    alphas[r] = expf(dt*Av);
    lams[r]   = lam;
    xbar[r]   = xraw[r] * (1.f/2048.f);
    atomicAdd(Asum, Av);
  }
}

// ---------------- kernel 3a: per-chunk angle sums ----------------
__global__ __launch_bounds__(64) void rope_sum_kernel(
    const float* __restrict__ dtth, float* __restrict__ csum)
{
  int b  = blockIdx.x >> 7;
  int ch = blockIdx.x & 127;
  int d  = threadIdx.x;
  const float* base = dtth + ((size_t)b*LSEQ + (size_t)ch*RCLEN)*64 + d;
  float s = 0.f;
  #pragma unroll
  for (int i = 0; i < RCLEN; ++i) s += base[(size_t)i*64];
  csum[((size_t)b*RCH + ch)*64 + d] = s;
}

// ---------------- kernel 3b: exclusive prefix over chunks (in place) -------
__global__ __launch_bounds__(64) void rope_prefix_kernel(float* __restrict__ csum)
{
  int b = blockIdx.x, d = threadIdx.x;
  float s = 0.f;
  for (int c = 0; c < RCH; ++c){
    size_t idx = ((size_t)b*RCH + c)*64 + d;
    float v = csum[idx]; csum[idx] = s; s += v;
  }
}

// ---------------- kernel 3c: rope apply with chunk offsets ----------------
__global__ __launch_bounds__(64) void rope_apply_kernel(
    const float* __restrict__ dtth, const float* __restrict__ csum,
    float* __restrict__ Bn, float* __restrict__ Cn)
{
  int b  = blockIdx.x >> 7;
  int ch = blockIdx.x & 127;
  int d  = threadIdx.x;
  float ca = csum[((size_t)b*RCH + ch)*64 + d];
  int l0 = ch*RCLEN;
  const float* base = dtth + ((size_t)b*LSEQ)*64 + d;
  for (int l = l0; l < l0 + RCLEN; ++l){
    ca += base[(size_t)l*64];
    float sn, cs;
    sincosf(ca, &sn, &cs);
    size_t ro = ((size_t)b*LSEQ + l)*128;
    float b1 = Bn[ro+d], b2v = Bn[ro+64+d];
    Bn[ro+d]    = b1*cs - b2v*sn;
    Bn[ro+64+d] = b1*sn + b2v*cs;
    float c1 = Cn[ro+d], c2v = Cn[ro+64+d];
    Cn[ro+d]    = c1*cs - c2v*sn;
    Cn[ro+64+d] = c1*sn + c2v*cs;
  }
}

// ---------------- kernel 4a: chunk-local scan ----------------
__global__ __launch_bounds__(64) void scan_local_kernel(
    const float* __restrict__ dts, const float* __restrict__ alphas,
    const float* __restrict__ lams, const float* __restrict__ xbar,
    const float* __restrict__ Asum,
    const float* __restrict__ Bn, const float* __restrict__ Cn,
    float* __restrict__ ylocal, float* __restrict__ Pfix,
    float* __restrict__ Sfin, float* __restrict__ Dch)
{
  int b  = blockIdx.x / SCHUNK;
  int ch = blockIdx.x % SCHUNK;
  int n  = threadIdx.x;
  float Abar = Asum[0] * (1.f/(float)ROWS);
  float s1 = 0.f, s2 = 0.f, P = 1.f;
  int l0 = ch*SCLEN;
  #pragma unroll
  for (int i = 0; i < SCLEN; ++i){
    int l = l0 + i;
    size_t r = (size_t)b*LSEQ + l;
    float dt = dts[r], lam = lams[r], al = alphas[r], xb = xbar[r];
    float xp = (l > 0) ? xbar[r-1] : 0.f;
    float um = lam*xb + (1.f-lam)*al*xp;
    float dA = expf(dt*Abar);
    float coef = dt*um;
    size_t ro = r*128;
    s1 = dA*s1 + coef*Bn[ro+n];
    s2 = dA*s2 + coef*Bn[ro+64+n];
    P *= dA;
    float p = s1*Cn[ro+n] + s2*Cn[ro+64+n];
    #pragma unroll
    for (int off = 32; off > 0; off >>= 1) p += __shfl_down(p, off);
    if (n == 0){ ylocal[r] = p; Pfix[r] = P; }
  }
  size_t so = ((size_t)b*SCHUNK + ch)*128;
  Sfin[so + n]      = s1;
  Sfin[so + 64 + n] = s2;
  if (n == 0) Dch[b*SCHUNK + ch] = P;
}

// ---------------- kernel 4b: inter-chunk carry ----------------
__global__ __launch_bounds__(128) void scan_carry_kernel(
    const float* __restrict__ Sfin, const float* __restrict__ Dch,
    float* __restrict__ Sin)
{
  int b = blockIdx.x;
  int n = threadIdx.x;
  float s = 0.f;
  for (int c = 0; c < SCHUNK; ++c){
    size_t so = ((size_t)b*SCHUNK + c)*128;
    Sin[so + n] = s;
    s = Dch[b*SCHUNK + c]*s + Sfin[so + n];
  }
}

// ---------------- kernel 4c: fixup ----------------
__global__ __launch_bounds__(256) void scan_fix_kernel(
    const float* __restrict__ Cn, const float* __restrict__ Sin,
    const float* __restrict__ ylocal, const float* __restrict__ Pfix,
    float* __restrict__ outsv)
{
  int r = blockIdx.x*4 + (threadIdx.x>>6);
  int n = threadIdx.x & 63;
  int b  = r / LSEQ;
  int ch = (r % LSEQ) / SCLEN;
  const float* si = Sin + ((size_t)b*SCHUNK + ch)*128;
  size_t ro = (size_t)r*128;
  float p = Cn[ro+n]*si[n] + Cn[ro+64+n]*si[64+n];
  #pragma unroll
  for (int off = 32; off > 0; off >>= 1) p += __shfl_down(p, off);
  if (n == 0) outsv[r] = ylocal[r] + Pfix[r]*p;
}

// ---------------- launch ----------------
extern "C" void kernel_launch(void* const* d_in, const int* in_sizes, int n_in,
                              void* d_out, int out_size, void* d_ws, size_t ws_size,
                              hipStream_t stream)
{
  const float* u    = (const float*)d_in[0];
  const float* W_in = (const float*)d_in[1];
  const float* wnB  = (const float*)d_in[2];
  const float* wnC  = (const float*)d_in[3];
  const float* Bb   = (const float*)d_in[4];
  const float* Cb   = (const float*)d_in[5];
  const float* dtb  = (const float*)d_in[6];
  const float* Alog = (const float*)d_in[7];
  const float* Wout = (const float*)d_in[8];
  float* out = (float*)d_out;
  char* ws = (char*)d_ws;

  constexpr size_t OFF_ASUM = 0;
  constexpr size_t OFF_UBF  = 256;
  constexpr size_t SZ_UBF   = (size_t)ROWS*LDU*2;
  constexpr size_t OFF_WIN  = OFF_UBF + SZ_UBF;
  constexpr size_t SZ_WIN   = (size_t)ZPAD*LDU*2;
  constexpr size_t OFF_WOUT = OFF_WIN + SZ_WIN;
  constexpr size_t SZ_WOUT  = (size_t)DMODEL*LDG*2;
  constexpr size_t OFF_G    = OFF_WOUT + SZ_WOUT;
  constexpr size_t SZ_G     = (size_t)ROWS*LDG*2;
  constexpr size_t OFF_ZS   = OFF_G + SZ_G;
  constexpr size_t SZ_ZS    = (size_t)ROWS*384*4;
  constexpr size_t OFF_BN   = OFF_ZS + SZ_ZS;
  constexpr size_t SZ_BN    = (size_t)ROWS*128*4;
  constexpr size_t OFF_CN   = OFF_BN + SZ_BN;
  constexpr size_t OFF_DTTH = OFF_CN + SZ_BN;
  constexpr size_t SZ_DTTH  = (size_t)ROWS*64*4;
  constexpr size_t OFF_XRAW = OFF_DTTH + SZ_DTTH;
  constexpr size_t OFF_DT   = OFF_XRAW + (size_t)ROWS*4;
  constexpr size_t OFF_AL   = OFF_DT  + (size_t)ROWS*4;
  constexpr size_t OFF_LAM  = OFF_AL  + (size_t)ROWS*4;
  constexpr size_t OFF_XB   = OFF_LAM + (size_t)ROWS*4;
  constexpr size_t OFF_OUTS = OFF_XB  + (size_t)ROWS*4;
  constexpr size_t OFF_YLOC = OFF_OUTS + (size_t)ROWS*4;
  constexpr size_t OFF_PFIX = OFF_YLOC + (size_t)ROWS*4;
  constexpr size_t OFF_SFIN = OFF_PFIX + (size_t)ROWS*4;
  constexpr size_t SZ_SFIN  = (size_t)B_SZ*SCHUNK*128*4;
  constexpr size_t OFF_DCH  = OFF_SFIN + SZ_SFIN;
  constexpr size_t OFF_SIN  = OFF_DCH + (size_t)B_SZ*SCHUNK*4;
  constexpr size_t OFF_CSUM = OFF_SIN + SZ_SFIN;

  float*  Asum   = (float*) (ws + OFF_ASUM);
  bf16_t* ubf    = (bf16_t*)(ws + OFF_UBF);
  bf16_t* winbf  = (bf16_t*)(ws + OFF_WIN);
  bf16_t* woutbf = (bf16_t*)(ws + OFF_WOUT);
  bf16_t* gbuf   = (bf16_t*)(ws + OFF_G);
  float*  zsb    = (float*) (ws + OFF_ZS);
  float*  Bn     = (float*) (ws + OFF_BN);
  float*  Cn     = (float*) (ws + OFF_CN);
  float*  dtth   = (float*) (ws + OFF_DTTH);
  float*  xraw   = (float*) (ws + OFF_XRAW);
  float*  dts    = (float*) (ws + OFF_DT);
  float*  alphas = (float*) (ws + OFF_AL);
  float*  lams   = (float*) (ws + OFF_LAM);
  float*  xbar   = (float*) (ws + OFF_XB);
  float*  outsv  = (float*) (ws + OFF_OUTS);
  float*  ylocal = (float*) (ws + OFF_YLOC);
  float*  Pfix   = (float*) (ws + OFF_PFIX);
  float*  Sfin   = (float*) (ws + OFF_SFIN);
  float*  Dch    = (float*) (ws + OFF_DCH);
  float*  Sin    = (float*) (ws + OFF_SIN);
  float*  csum   = (float*) (ws + OFF_CSUM);

  {
    size_t total4 = ((size_t)ROWS*DMODEL + (size_t)ZPAD*DMODEL + (size_t)DMODEL*EDIM)/4;
    int blocks = (int)((total4 + 255)/256);
    prep_kernel<<<blocks, 256, 0, stream>>>(
        (const float4*)u, (const float4*)W_in, (const float4*)Wout,
        ubf, winbf, woutbf, Asum, xraw);
  }
  hipMemsetAsync(out, 0, (size_t)ROWS*DMODEL*sizeof(float), stream);

  // GEMM1: 256x128 tiles, NCH=4 (K=1024), grid = 36 x 32 = 1152, 2 blocks/CU
  gemmAD_kernel<LDU, LDU, 4, ZPAD/128, 0>
      <<<(ZPAD/128)*(ROWS/256), 256, 0, stream>>>(
      ubf, winbf, xraw, gbuf, zsb, nullptr, nullptr);
  fuse_kernel<<<ROWS, 128, 0, stream>>>(xraw, zsb, wnB, wnC, Bb, Cb, dtb, Alog,
                                        Bn, Cn, dtth, dts, alphas, lams, xbar, Asum);
  rope_sum_kernel<<<B_SZ*RCH, 64, 0, stream>>>(dtth, csum);
  rope_prefix_kernel<<<B_SZ, 64, 0, stream>>>(csum);
  rope_apply_kernel<<<B_SZ*RCH, 64, 0, stream>>>(dtth, csum, Bn, Cn);
  scan_local_kernel<<<B_SZ*SCHUNK, 64, 0, stream>>>(dts, alphas, lams, xbar, Asum,
                                                    Bn, Cn, ylocal, Pfix, Sfin, Dch);
  scan_carry_kernel<<<B_SZ, 128, 0, stream>>>(Sfin, Dch, Sin);
  scan_fix_kernel<<<ROWS/4, 256, 0, stream>>>(Cn, Sin, ylocal, Pfix, outsv);
  // GEMM2: split-K x2 (K=1024 each), 256x128 tiles, grid = 2x8x32 = 512, 2/CU
  gemmAD_kernel<LDG, LDG, 4, DMODEL/128, 1>
      <<<2*(DMODEL/128)*(ROWS/256), 256, 0, stream>>>(
      gbuf, woutbf, nullptr, nullptr, nullptr, outsv, out);
}

// Round 11
// 389.804 us; speedup vs baseline: 1.4191x; 1.4191x over previous
//
#include <hip/hip_runtime.h>
#include <cstdint>
#include <cstddef>

typedef __bf16 bf16_t;
typedef bf16_t bf16x8 __attribute__((ext_vector_type(8)));
typedef bf16_t bf16x4 __attribute__((ext_vector_type(4)));
typedef float f32x4 __attribute__((ext_vector_type(4)));

#define B_SZ    4
#define LSEQ    2048
#define DMODEL  1024
#define EDIM    2048
#define ZDIM    4419
#define ZPAD    4608
#define ROWS    (B_SZ*LSEQ)     /* 8192 */
#define EPSV    1e-5f

/* padded leading dims */
#define LDU     1088
#define LDG     2112

#define SCHUNK  128
#define SCLEN   (LSEQ/SCHUNK)   /* 16 */
#define RCH     128
#define RCLEN   (LSEQ/RCH)      /* 16 */

// ---------------- helpers ----------------
__device__ __forceinline__ float softplus_f(float x){
  return fmaxf(x, 0.f) + log1pf(expf(-fabsf(x)));
}
__device__ __forceinline__ float sigmoid_f(float x){ return 1.f/(1.f+expf(-x)); }
__device__ __forceinline__ float silu_f(float x){ return x/(1.f+expf(-x)); }

__device__ __forceinline__ void gload_lds16(const void* g, void* l){
  __builtin_amdgcn_global_load_lds(
      (const __attribute__((address_space(1))) void*)g,
      (__attribute__((address_space(3))) void*)l, 16, 0, 0);
}

__device__ __forceinline__ float blockReduce128(float v, float* red, int t){
  red[t] = v; __syncthreads();
  #pragma unroll
  for (int off = 64; off > 0; off >>= 1){
    if (t < off) red[t] += red[t+off];
    __syncthreads();
  }
  float r = red[0];
  __syncthreads();
  return r;
}

// ---------------- kernel 0: vectorized casts + zero accumulators -----------
__global__ __launch_bounds__(256) void prep_kernel(
    const float4* __restrict__ u4, const float4* __restrict__ win4,
    const float4* __restrict__ wout4,
    bf16_t* __restrict__ ubf, bf16_t* __restrict__ winbf, bf16_t* __restrict__ woutbf,
    float* __restrict__ Asum, float* __restrict__ xraw)
{
  size_t i = (size_t)blockIdx.x*256 + threadIdx.x;
  if (i == 0) Asum[0] = 0.f;
  if (i < ROWS) xraw[i] = 0.f;
  const size_t NU4 = (size_t)ROWS*DMODEL/4;
  const size_t NW4 = (size_t)ZPAD*DMODEL/4;
  const size_t NO4 = (size_t)DMODEL*EDIM/4;
  if (i < NU4){
    float4 v = u4[i];
    size_t e = i*4, row = e>>10, col = e&1023;
    bf16x4 o = { (bf16_t)v.x, (bf16_t)v.y, (bf16_t)v.z, (bf16_t)v.w };
    *(bf16x4*)&ubf[row*LDU + col] = o;
    return;
  }
  i -= NU4;
  if (i < NW4){
    size_t e = i*4, row = e>>10, col = e&1023;
    bf16x4 o;
    if (row < (size_t)ZDIM){
      float4 v = win4[i];
      o = bf16x4{ (bf16_t)v.x, (bf16_t)v.y, (bf16_t)v.z, (bf16_t)v.w };
    } else {
      o = bf16x4{ (bf16_t)0.f, (bf16_t)0.f, (bf16_t)0.f, (bf16_t)0.f };
    }
    *(bf16x4*)&winbf[row*LDU + col] = o;
    return;
  }
  i -= NW4;
  if (i < NO4){
    float4 v = wout4[i];
    size_t e = i*4, row = e>>11, col = e&2047;
    bf16x4 o = { (bf16_t)v.x, (bf16_t)v.y, (bf16_t)v.z, (bf16_t)v.w };
    *(bf16x4*)&woutbf[row*LDG + col] = o;
  }
}

// -------- m97-replica GEMM: 128x128, BK=32, single 16KB LDS buffer --------
// C = A[M][LDA_] @ W[N][LDW_]^T, bf16 row-major, K = NT*32 per block.
// 256 thr = 4 waves (2x2), per-wave 64x64 output, acc[4][4] = 64 AGPR.
// Per K-step: { 4 x gload_lds16 | __syncthreads (compiler drains) |
//               8 x ds_read_b128 + 16 MFMA (compiler-scheduled lgkmcnt) |
//               __syncthreads }.  No inline asm: multi-block TLP (target 3
// blocks/CU, ~140 total regs) hides barrier drains (m97/m114 mechanism).
// Rotation swizzle on 64B LDS rows: store chunk dch holds global chunk
// (dch-(row>>1))&3; read chunk (hi+(row>>1))&3 -> bank-quad (4r+c)%8 covers
// all 8 quads over 8 rows -> 2-way max (free). Source pre-swizzled (rule 21).
// MODE 0 (GEMM1): n0<2048 -> silu row-sum atomics into xraw;
//   2048..4095 -> silu -> o_g (stride LDG); 4096..4479 -> o_z fp32.
// MODE 1 (GEMM2 split-K x2): atomicAdd(o_f, acc*scale[row]).
template<int LDA_, int LDW_, int NT, int NXT, int MODE>
__global__ __launch_bounds__(256) void gemmM_kernel(
    const bf16_t* __restrict__ A0, const bf16_t* __restrict__ W0,
    float* __restrict__ xraw, bf16_t* __restrict__ o_g, float* __restrict__ o_z,
    const float* __restrict__ scale, float* __restrict__ o_f)
{
  __shared__ __align__(16) bf16_t lds[8192];   // A [0,4096), B [4096,8192)

  const int tid = threadIdx.x;
  const int wid = tid>>6, lane = tid&63;
  const int wr = wid>>1, wc = wid&1;
  const int lr = lane&15, hi = lane>>4;

  constexpr int NWG = (MODE==0) ? NXT*(ROWS/128) : NXT*(ROWS/128)*2;
  const int id = blockIdx.x;
  const int rid = (id & 7)*(NWG/8) + (id>>3);    // bijective (NWG%8==0)
  int bx, by, kz = 0;
  if (MODE == 0){ bx = rid % NXT; by = rid / NXT; }
  else { kz = rid / (NXT*(ROWS/128)); int r2 = rid % (NXT*(ROWS/128));
         bx = r2 % NXT; by = r2 / NXT; }
  const int m0 = by*128, n0 = bx*128;
  const size_t kzo = (size_t)kz*1024;

  f32x4 acc[4][4] = {};

  // ---- staging pointers (pre-swizzled source), advance +32/step ----
  const bf16_t* pA[2]; const bf16_t* pW[2];
  int dstA[2], dstB[2];
  #pragma unroll
  for (int q = 0; q < 2; ++q){
    int cidx = q*256 + tid;
    int row = cidx>>2, dch = cidx&3;
    int gs = (dch - (row>>1)) & 3;
    pA[q] = A0 + kzo + (size_t)(m0+row)*LDA_ + gs*8;
    pW[q] = W0 + kzo + (size_t)(n0+row)*LDW_ + gs*8;
    dstA[q] = cidx*8;
    dstB[q] = 4096 + cidx*8;
  }

  // ---- loop-invariant read offsets (chunk rotation is m/n-invariant) ----
  int aoff[4], boff[4];
  {
    int R0 = wr*64 + lr;
    int cA = (hi + (R0>>1)) & 3;
    #pragma unroll
    for (int m = 0; m < 4; ++m) aoff[m] = (R0 + 16*m)*32 + cA*8;
    int R0b = wc*64 + lr;
    int cB = (hi + (R0b>>1)) & 3;
    #pragma unroll
    for (int n = 0; n < 4; ++n) boff[n] = 4096 + (R0b + 16*n)*32 + cB*8;
  }

  #pragma unroll 1
  for (int t = 0; t < NT; ++t){
    gload_lds16(pA[0], &lds[dstA[0]]);
    gload_lds16(pA[1], &lds[dstA[1]]);
    gload_lds16(pW[0], &lds[dstB[0]]);
    gload_lds16(pW[1], &lds[dstB[1]]);
    pA[0] += 32; pA[1] += 32; pW[0] += 32; pW[1] += 32;
    __syncthreads();
    bf16x8 bfr[4];
    #pragma unroll
    for (int n = 0; n < 4; ++n) bfr[n] = *(const bf16x8*)&lds[boff[n]];
    #pragma unroll
    for (int m = 0; m < 4; ++m){
      bf16x8 af = *(const bf16x8*)&lds[aoff[m]];
      #pragma unroll
      for (int n = 0; n < 4; ++n)
        acc[m][n] = __builtin_amdgcn_mfma_f32_16x16x32_bf16(af, bfr[n], acc[m][n], 0,0,0);
    }
    __syncthreads();
  }

  // ---- epilogue (row = m0 + wr*64 + m*16 + hi*4 + i; col = n0 + wc*64 + n*16 + lr)
  if (MODE == 0 && n0 < 2048){
    #pragma unroll
    for (int m = 0; m < 4; ++m){
      #pragma unroll
      for (int i = 0; i < 4; ++i){
        float p = 0.f;
        #pragma unroll
        for (int n = 0; n < 4; ++n) p += silu_f(acc[m][n][i]);
        p += __shfl_xor(p, 8); p += __shfl_xor(p, 4);
        p += __shfl_xor(p, 2); p += __shfl_xor(p, 1);
        if (lr == 0){
          int r = m0 + wr*64 + m*16 + (hi<<2) + i;
          atomicAdd(xraw + r, p);
        }
      }
    }
  } else if (MODE == 0){
    #pragma unroll
    for (int m = 0; m < 4; ++m){
      int rowb = m0 + wr*64 + m*16 + (hi<<2);
      #pragma unroll
      for (int n = 0; n < 4; ++n){
        int col = n0 + wc*64 + n*16 + lr;
        #pragma unroll
        for (int i = 0; i < 4; ++i){
          int r = rowb + i;
          float v = acc[m][n][i];
          if (col < 4096)      o_g[(size_t)r*LDG + (col-2048)] = (bf16_t)silu_f(v);
          else if (col < 4480) o_z[(size_t)r*384 + (col-4096)] = v;
        }
      }
    }
  } else {
    #pragma unroll
    for (int m = 0; m < 4; ++m){
      int rowb = m0 + wr*64 + m*16 + (hi<<2);
      #pragma unroll
      for (int i = 0; i < 4; ++i){
        int r = rowb + i;
        float s = scale[r];
        #pragma unroll
        for (int n = 0; n < 4; ++n){
          int col = n0 + wc*64 + n*16 + lr;
          atomicAdd(o_f + (size_t)r*DMODEL + col, acc[m][n][i]*s);
        }
      }
    }
  }
}

// ---------------- kernel 2: per-token fuse (RMS + scalars) ----------------
__global__ __launch_bounds__(128) void fuse_kernel(
    const float* __restrict__ xraw, const float* __restrict__ zs,
    const float* __restrict__ wnB, const float* __restrict__ wnC,
    const float* __restrict__ Bb, const float* __restrict__ Cb,
    const float* __restrict__ dtb, const float* __restrict__ Alog,
    float* __restrict__ Bn, float* __restrict__ Cn, float* __restrict__ dtth,
    float* __restrict__ dts, float* __restrict__ alphas, float* __restrict__ lams,
    float* __restrict__ xbar, float* Asum)
{
  __shared__ float red[128];
  int r = blockIdx.x, t = threadIdx.x;
  const float* zr = zs + (size_t)r*384;
  float bv = zr[t], cv = zr[128+t];
  float b2 = blockReduce128(bv*bv, red, t);
  float c2 = blockReduce128(cv*cv, red, t);
  float rb = rsqrtf(b2*(1.f/128.f) + EPSV);
  float rc = rsqrtf(c2*(1.f/128.f) + EPSV);
  Bn[(size_t)r*128 + t] = bv*rb*wnB[t] + Bb[t];
  Cn[(size_t)r*128 + t] = cv*rc*wnC[t] + Cb[t];

  float dt = softplus_f(zr[256] + dtb[0]);
  if (t < 64) dtth[(size_t)r*64 + t] = dt * zr[258+t];
  if (t == 0){
    float Av  = -softplus_f(zr[257] + Alog[0]);
    float lam = sigmoid_f(zr[322]);
    dts[r]    = dt;
    alphas[r] = expf(dt*Av);
    lams[r]   = lam;
    xbar[r]   = xraw[r] * (1.f/2048.f);
    atomicAdd(Asum, Av);
  }
}

// ---------------- kernel 3a: per-chunk angle sums ----------------
__global__ __launch_bounds__(64) void rope_sum_kernel(
    const float* __restrict__ dtth, float* __restrict__ csum)
{
  int b  = blockIdx.x >> 7;
  int ch = blockIdx.x & 127;
  int d  = threadIdx.x;
  const float* base = dtth + ((size_t)b*LSEQ + (size_t)ch*RCLEN)*64 + d;
  float s = 0.f;
  #pragma unroll
  for (int i = 0; i < RCLEN; ++i) s += base[(size_t)i*64];
  csum[((size_t)b*RCH + ch)*64 + d] = s;
}

// ---------------- kernel 3b: exclusive prefix over chunks (in place) -------
__global__ __launch_bounds__(64) void rope_prefix_kernel(float* __restrict__ csum)
{
  int b = blockIdx.x, d = threadIdx.x;
  float s = 0.f;
  for (int c = 0; c < RCH; ++c){
    size_t idx = ((size_t)b*RCH + c)*64 + d;
    float v = csum[idx]; csum[idx] = s; s += v;
  }
}

// ---------------- kernel 3c: rope apply with chunk offsets ----------------
__global__ __launch_bounds__(64) void rope_apply_kernel(
    const float* __restrict__ dtth, const float* __restrict__ csum,
    float* __restrict__ Bn, float* __restrict__ Cn)
{
  int b  = blockIdx.x >> 7;
  int ch = blockIdx.x & 127;
  int d  = threadIdx.x;
  float ca = csum[((size_t)b*RCH + ch)*64 + d];
  int l0 = ch*RCLEN;
  const float* base = dtth + ((size_t)b*LSEQ)*64 + d;
  for (int l = l0; l < l0 + RCLEN; ++l){
    ca += base[(size_t)l*64];
    float sn, cs;
    sincosf(ca, &sn, &cs);
    size_t ro = ((size_t)b*LSEQ + l)*128;
    float b1 = Bn[ro+d], b2v = Bn[ro+64+d];
    Bn[ro+d]    = b1*cs - b2v*sn;
    Bn[ro+64+d] = b1*sn + b2v*cs;
    float c1 = Cn[ro+d], c2v = Cn[ro+64+d];
    Cn[ro+d]    = c1*cs - c2v*sn;
    Cn[ro+64+d] = c1*sn + c2v*cs;
  }
}

// ---------------- kernel 4a: chunk-local scan ----------------
__global__ __launch_bounds__(64) void scan_local_kernel(
    const float* __restrict__ dts, const float* __restrict__ alphas,
    const float* __restrict__ lams, const float* __restrict__ xbar,
    const float* __restrict__ Asum,
    const float* __restrict__ Bn, const float* __restrict__ Cn,
    float* __restrict__ ylocal, float* __restrict__ Pfix,
    float* __restrict__ Sfin, float* __restrict__ Dch)
{
  int b  = blockIdx.x / SCHUNK;
  int ch = blockIdx.x % SCHUNK;
  int n  = threadIdx.x;
  float Abar = Asum[0] * (1.f/(float)ROWS);
  float s1 = 0.f, s2 = 0.f, P = 1.f;
  int l0 = ch*SCLEN;
  #pragma unroll
  for (int i = 0; i < SCLEN; ++i){
    int l = l0 + i;
    size_t r = (size_t)b*LSEQ + l;
    float dt = dts[r], lam = lams[r], al = alphas[r], xb = xbar[r];
    float xp = (l > 0) ? xbar[r-1] : 0.f;
    float um = lam*xb + (1.f-lam)*al*xp;
    float dA = expf(dt*Abar);
    float coef = dt*um;
    size_t ro = r*128;
    s1 = dA*s1 + coef*Bn[ro+n];
    s2 = dA*s2 + coef*Bn[ro+64+n];
    P *= dA;
    float p = s1*Cn[ro+n] + s2*Cn[ro+64+n];
    #pragma unroll
    for (int off = 32; off > 0; off >>= 1) p += __shfl_down(p, off);
    if (n == 0){ ylocal[r] = p; Pfix[r] = P; }
  }
  size_t so = ((size_t)b*SCHUNK + ch)*128;
  Sfin[so + n]      = s1;
  Sfin[so + 64 + n] = s2;
  if (n == 0) Dch[b*SCHUNK + ch] = P;
}

// ---------------- kernel 4b: inter-chunk carry ----------------
__global__ __launch_bounds__(128) void scan_carry_kernel(
    const float* __restrict__ Sfin, const float* __restrict__ Dch,
    float* __restrict__ Sin)
{
  int b = blockIdx.x;
  int n = threadIdx.x;
  float s = 0.f;
  for (int c = 0; c < SCHUNK; ++c){
    size_t so = ((size_t)b*SCHUNK + c)*128;
    Sin[so + n] = s;
    s = Dch[b*SCHUNK + c]*s + Sfin[so + n];
  }
}

// ---------------- kernel 4c: fixup ----------------
__global__ __launch_bounds__(256) void scan_fix_kernel(
    const float* __restrict__ Cn, const float* __restrict__ Sin,
    const float* __restrict__ ylocal, const float* __restrict__ Pfix,
    float* __restrict__ outsv)
{
  int r = blockIdx.x*4 + (threadIdx.x>>6);
  int n = threadIdx.x & 63;
  int b  = r / LSEQ;
  int ch = (r % LSEQ) / SCLEN;
  const float* si = Sin + ((size_t)b*SCHUNK + ch)*128;
  size_t ro = (size_t)r*128;
  float p = Cn[ro+n]*si[n] + Cn[ro+64+n]*si[64+n];
  #pragma unroll
  for (int off = 32; off > 0; off >>= 1) p += __shfl_down(p, off);
  if (n == 0) outsv[r] = ylocal[r] + Pfix[r]*p;
}

// ---------------- launch ----------------
extern "C" void kernel_launch(void* const* d_in, const int* in_sizes, int n_in,
                              void* d_out, int out_size, void* d_ws, size_t ws_size,
                              hipStream_t stream)
{
  const float* u    = (const float*)d_in[0];
  const float* W_in = (const float*)d_in[1];
  const float* wnB  = (const float*)d_in[2];
  const float* wnC  = (const float*)d_in[3];
  const float* Bb   = (const float*)d_in[4];
  const float* Cb   = (const float*)d_in[5];
  const float* dtb  = (const float*)d_in[6];
  const float* Alog = (const float*)d_in[7];
  const float* Wout = (const float*)d_in[8];
  float* out = (float*)d_out;
  char* ws = (char*)d_ws;

  constexpr size_t OFF_ASUM = 0;
  constexpr size_t OFF_UBF  = 256;
  constexpr size_t SZ_UBF   = (size_t)ROWS*LDU*2;
  constexpr size_t OFF_WIN  = OFF_UBF + SZ_UBF;
  constexpr size_t SZ_WIN   = (size_t)ZPAD*LDU*2;
  constexpr size_t OFF_WOUT = OFF_WIN + SZ_WIN;
  constexpr size_t SZ_WOUT  = (size_t)DMODEL*LDG*2;
  constexpr size_t OFF_G    = OFF_WOUT + SZ_WOUT;
  constexpr size_t SZ_G     = (size_t)ROWS*LDG*2;
  constexpr size_t OFF_ZS   = OFF_G + SZ_G;
  constexpr size_t SZ_ZS    = (size_t)ROWS*384*4;
  constexpr size_t OFF_BN   = OFF_ZS + SZ_ZS;
  constexpr size_t SZ_BN    = (size_t)ROWS*128*4;
  constexpr size_t OFF_CN   = OFF_BN + SZ_BN;
  constexpr size_t OFF_DTTH = OFF_CN + SZ_BN;
  constexpr size_t SZ_DTTH  = (size_t)ROWS*64*4;
  constexpr size_t OFF_XRAW = OFF_DTTH + SZ_DTTH;
  constexpr size_t OFF_DT   = OFF_XRAW + (size_t)ROWS*4;
  constexpr size_t OFF_AL   = OFF_DT  + (size_t)ROWS*4;
  constexpr size_t OFF_LAM  = OFF_AL  + (size_t)ROWS*4;
  constexpr size_t OFF_XB   = OFF_LAM + (size_t)ROWS*4;
  constexpr size_t OFF_OUTS = OFF_XB  + (size_t)ROWS*4;
  constexpr size_t OFF_YLOC = OFF_OUTS + (size_t)ROWS*4;
  constexpr size_t OFF_PFIX = OFF_YLOC + (size_t)ROWS*4;
  constexpr size_t OFF_SFIN = OFF_PFIX + (size_t)ROWS*4;
  constexpr size_t SZ_SFIN  = (size_t)B_SZ*SCHUNK*128*4;
  constexpr size_t OFF_DCH  = OFF_SFIN + SZ_SFIN;
  constexpr size_t OFF_SIN  = OFF_DCH + (size_t)B_SZ*SCHUNK*4;
  constexpr size_t OFF_CSUM = OFF_SIN + SZ_SFIN;

  float*  Asum   = (float*) (ws + OFF_ASUM);
  bf16_t* ubf    = (bf16_t*)(ws + OFF_UBF);
  bf16_t* winbf  = (bf16_t*)(ws + OFF_WIN);
  bf16_t* woutbf = (bf16_t*)(ws + OFF_WOUT);
  bf16_t* gbuf   = (bf16_t*)(ws + OFF_G);
  float*  zsb    = (float*) (ws + OFF_ZS);
  float*  Bn     = (float*) (ws + OFF_BN);
  float*  Cn     = (float*) (ws + OFF_CN);
  float*  dtth   = (float*) (ws + OFF_DTTH);
  float*  xraw   = (float*) (ws + OFF_XRAW);
  float*  dts    = (float*) (ws + OFF_DT);
  float*  alphas = (float*) (ws + OFF_AL);
  float*  lams   = (float*) (ws + OFF_LAM);
  float*  xbar   = (float*) (ws + OFF_XB);
  float*  outsv  = (float*) (ws + OFF_OUTS);
  float*  ylocal = (float*) (ws + OFF_YLOC);
  float*  Pfix   = (float*) (ws + OFF_PFIX);
  float*  Sfin   = (float*) (ws + OFF_SFIN);
  float*  Dch    = (float*) (ws + OFF_DCH);
  float*  Sin    = (float*) (ws + OFF_SIN);
  float*  csum   = (float*) (ws + OFF_CSUM);

  {
    size_t total4 = ((size_t)ROWS*DMODEL + (size_t)ZPAD*DMODEL + (size_t)DMODEL*EDIM)/4;
    int blocks = (int)((total4 + 255)/256);
    prep_kernel<<<blocks, 256, 0, stream>>>(
        (const float4*)u, (const float4*)W_in, (const float4*)Wout,
        ubf, winbf, woutbf, Asum, xraw);
  }
  hipMemsetAsync(out, 0, (size_t)ROWS*DMODEL*sizeof(float), stream);

  // GEMM1: 128x128 tiles, grid = 36 x 64 = 2304 blocks, target 3 blocks/CU
  gemmM_kernel<LDU, LDU, 32, ZPAD/128, 0>
      <<<(ZPAD/128)*(ROWS/128), 256, 0, stream>>>(
      ubf, winbf, xraw, gbuf, zsb, nullptr, nullptr);
  fuse_kernel<<<ROWS, 128, 0, stream>>>(xraw, zsb, wnB, wnC, Bb, Cb, dtb, Alog,
                                        Bn, Cn, dtth, dts, alphas, lams, xbar, Asum);
  rope_sum_kernel<<<B_SZ*RCH, 64, 0, stream>>>(dtth, csum);
  rope_prefix_kernel<<<B_SZ, 64, 0, stream>>>(csum);
  rope_apply_kernel<<<B_SZ*RCH, 64, 0, stream>>>(dtth, csum, Bn, Cn);
  scan_local_kernel<<<B_SZ*SCHUNK, 64, 0, stream>>>(dts, alphas, lams, xbar, Asum,
                                                    Bn, Cn, ylocal, Pfix, Sfin, Dch);
  scan_carry_kernel<<<B_SZ, 128, 0, stream>>>(Sfin, Dch, Sin);
  scan_fix_kernel<<<ROWS/4, 256, 0, stream>>>(Cn, Sin, ylocal, Pfix, outsv);
  // GEMM2: split-K x2 (K=1024 each), 128x128 tiles, grid = 2x8x64 = 1024
  gemmM_kernel<LDG, LDG, 32, DMODEL/128, 1>
      <<<2*(DMODEL/128)*(ROWS/128), 256, 0, stream>>>(
      gbuf, woutbf, nullptr, nullptr, nullptr, outsv, out);
}

// Round 12
// 382.020 us; speedup vs baseline: 1.4480x; 1.0204x over previous
//
#include <hip/hip_runtime.h>
#include <cstdint>
#include <cstddef>

typedef __bf16 bf16_t;
typedef bf16_t bf16x8 __attribute__((ext_vector_type(8)));
typedef bf16_t bf16x4 __attribute__((ext_vector_type(4)));
typedef float f32x4 __attribute__((ext_vector_type(4)));

#define B_SZ    4
#define LSEQ    2048
#define DMODEL  1024
#define EDIM    2048
#define ZDIM    4419
#define ZPAD    4608
#define ROWS    (B_SZ*LSEQ)     /* 8192 */
#define EPSV    1e-5f

/* padded leading dims for row-major A operands */
#define LDU     1088
#define LDG     2112

#define SCHUNK  128
#define SCLEN   (LSEQ/SCHUNK)   /* 16 */
#define RCH     128
#define RCLEN   (LSEQ/RCH)      /* 16 */

// ---------------- helpers ----------------
__device__ __forceinline__ float softplus_f(float x){
  return fmaxf(x, 0.f) + log1pf(expf(-fabsf(x)));
}
__device__ __forceinline__ float sigmoid_f(float x){ return 1.f/(1.f+expf(-x)); }
__device__ __forceinline__ float silu_f(float x){ return x/(1.f+expf(-x)); }

__device__ __forceinline__ void gload_lds16(const void* g, void* l){
  __builtin_amdgcn_global_load_lds(
      (const __attribute__((address_space(1))) void*)g,
      (__attribute__((address_space(3))) void*)l, 16, 0, 0);
}

__device__ __forceinline__ float blockReduce128(float v, float* red, int t){
  red[t] = v; __syncthreads();
  #pragma unroll
  for (int off = 64; off > 0; off >>= 1){
    if (t < off) red[t] += red[t+off];
    __syncthreads();
  }
  float r = red[0];
  __syncthreads();
  return r;
}

// ---------------- kernel 0: casts; W -> fragment-linear shuffled layout ----
// B-frag layout (MFMA 16x16x32 bf16 B operand): for (ntile = n>>4,
// kt = k>>5): 1KB block of 64 lanes x 16B, lane = koct*16 + (n&15),
// holding W[n][kt*32 + koct*8 .. +8].  offset(elems) =
// (ntile*NKT + kt)*512 + koct*128 + (n&15)*8 + (k&7).
__global__ __launch_bounds__(256) void prep_kernel(
    const float4* __restrict__ u4, const float4* __restrict__ win4,
    const float4* __restrict__ wout4,
    bf16_t* __restrict__ ubf, bf16_t* __restrict__ winSh, bf16_t* __restrict__ woutSh,
    float* __restrict__ Asum, float* __restrict__ xraw)
{
  size_t i = (size_t)blockIdx.x*256 + threadIdx.x;
  if (i == 0) Asum[0] = 0.f;
  if (i < ROWS) xraw[i] = 0.f;
  const size_t NU4 = (size_t)ROWS*DMODEL/4;
  const size_t NW4 = (size_t)ZPAD*DMODEL/4;
  const size_t NO4 = (size_t)DMODEL*EDIM/4;
  if (i < NU4){
    float4 v = u4[i];
    size_t e = i*4, row = e>>10, col = e&1023;
    bf16x4 o = { (bf16_t)v.x, (bf16_t)v.y, (bf16_t)v.z, (bf16_t)v.w };
    *(bf16x4*)&ubf[row*LDU + col] = o;
    return;
  }
  i -= NU4;
  if (i < NW4){
    size_t e = i*4, row = e>>10, k = e&1023;
    bf16x4 o;
    if (row < (size_t)ZDIM){
      float4 v = win4[i];
      o = bf16x4{ (bf16_t)v.x, (bf16_t)v.y, (bf16_t)v.z, (bf16_t)v.w };
    } else {
      o = bf16x4{ (bf16_t)0.f, (bf16_t)0.f, (bf16_t)0.f, (bf16_t)0.f };
    }
    int ntile = (int)(row>>4), colf = (int)(row&15);
    int kt = (int)(k>>5), koct = (int)((k>>3)&3), ko = (int)(k&7);
    size_t off = (((size_t)ntile*32 + kt)<<9) + (koct<<7) + (colf<<3) + ko;
    *(bf16x4*)&winSh[off] = o;
    return;
  }
  i -= NW4;
  if (i < NO4){
    float4 v = wout4[i];
    size_t e = i*4, row = e>>11, k = e&2047;
    bf16x4 o = { (bf16_t)v.x, (bf16_t)v.y, (bf16_t)v.z, (bf16_t)v.w };
    int ntile = (int)(row>>4), colf = (int)(row&15);
    int kt = (int)(k>>5), koct = (int)((k>>3)&3), ko = (int)(k&7);
    size_t off = (((size_t)ntile*64 + kt)<<9) + (koct<<7) + (colf<<3) + ko;
    *(bf16x4*)&woutSh[off] = o;
  }
}

// -------- GEMM-V: A via LDS-DMA (8KB/step), B direct global->VGPR ---------
// C = A[M][LDA_] @ W[N][.]^T; W pre-shuffled fragment-linear (NKT k-tiles).
// 128 x 256 tile, K = NT*32 per block. 256 thr = 4 waves (2Mx2N),
// per-wave 64x128: acc[4][8]. A double-buffered in 16KB LDS (rotation
// swizzle, R11-verified); B fragments = 8 coalesced global_load_dwordx4
// per wave per step, register double-buffered via even/odd step unroll.
// Counted wait: issue {2 A-DMA, 8 B-loads} then vmcnt(8) -> retires exactly
// the DMAs, leaves B in flight (compiler tracks B-reg waits itself).
// 2 blocks/CU (launch_bounds(256,2)). Bijective XCD swizzle.
// MODE 0 (GEMM1): bx<8 -> silu row-sum atomics into xraw;
//   bx 8..15 -> silu -> o_g (stride LDG); bx 16,17 -> o_z fp32 (col<4480).
// MODE 1 (GEMM2 split-K x2): atomicAdd(o_f, acc*scale[row]).
template<int LDA_, int NKT, int NT, int NXT, int MODE>
__global__ __launch_bounds__(256, 2) void gemmV_kernel(
    const bf16_t* __restrict__ A0, const bf16_t* __restrict__ Bsh,
    float* __restrict__ xraw, bf16_t* __restrict__ o_g, float* __restrict__ o_z,
    const float* __restrict__ scale, float* __restrict__ o_f)
{
  __shared__ __align__(16) bf16_t lds[8192];   // two 4096-elem A buffers

  const int tid = threadIdx.x;
  const int wid = tid>>6, lane = tid&63;
  const int wr = wid>>1, wc = wid&1;
  const int lr = lane&15, hi = lane>>4;

  constexpr int MB = ROWS/128;                 // 64
  constexpr int NWG = (MODE==0) ? NXT*MB : NXT*MB*2;
  const int id = blockIdx.x;
  const int rid = (id & 7)*(NWG/8) + (id>>3);  // bijective (NWG%8==0)
  int bx, by, kz = 0;
  if (MODE == 0){ bx = rid % NXT; by = rid / NXT; }
  else { kz = rid / (NXT*MB); int r2 = rid % (NXT*MB); bx = r2 % NXT; by = r2 / NXT; }
  const int m0 = by*128, n0 = bx*256;
  const int kt0 = kz*32;

  f32x4 acc[4][8] = {};

  // ---- A staging pointers (rotation swizzle, source-side) ----
  const bf16_t* pA0; const bf16_t* pA1;
  int dA0, dA1;
  {
    int c0 = tid,      r0 = c0>>2, d0 = c0&3, g0 = (d0 - (r0>>1)) & 3;
    int c1 = 256+tid,  r1 = c1>>2, d1 = c1&3, g1 = (d1 - (r1>>1)) & 3;
    pA0 = A0 + (size_t)kz*1024 + (size_t)(m0+r0)*LDA_ + g0*8;
    pA1 = A0 + (size_t)kz*1024 + (size_t)(m0+r1)*LDA_ + g1*8;
    dA0 = c0*8; dA1 = c1*8;
  }
  // ---- A read offsets (read-side rotation) ----
  int aoff[4];
  {
    int R0 = wr*64 + lr;
    int cA = (hi + (R0>>1)) & 3;
    #pragma unroll
    for (int m = 0; m < 4; ++m) aoff[m] = (R0 + 16*m)*32 + cA*8;
  }
  // ---- B fragment base (per-lane, coalesced 1KB per frag) ----
  const bf16_t* bB0 = Bsh + (((size_t)((n0>>4) + wc*8)*NKT + kt0)<<9) + lane*8;
  int koff = 0;

  bf16x8 bA[8], bB[8], af[4];

  // ---- prologue: stage A(t0) -> buf0; load B(t0) ----
  gload_lds16(pA0, &lds[dA0]); pA0 += 32;
  gload_lds16(pA1, &lds[dA1]); pA1 += 32;
  #pragma unroll
  for (int n = 0; n < 8; ++n)
    bA[n] = *(const bf16x8*)(bB0 + (size_t)n*(NKT*512) + koff);
  koff += 512;
  asm volatile("s_waitcnt vmcnt(8)" ::: "memory");
  __builtin_amdgcn_s_barrier();

  #pragma unroll 1
  for (int t2 = 0; t2 < NT/2; ++t2){
    // ---- even step: read buf0, cur=bA; prefetch (t+1) -> buf1, bB ----
    {
      #pragma unroll
      for (int m = 0; m < 4; ++m) af[m] = *(const bf16x8*)&lds[aoff[m]];
      gload_lds16(pA0, &lds[4096 + dA0]); pA0 += 32;
      gload_lds16(pA1, &lds[4096 + dA1]); pA1 += 32;
      #pragma unroll
      for (int n = 0; n < 8; ++n)
        bB[n] = *(const bf16x8*)(bB0 + (size_t)n*(NKT*512) + koff);
      koff += 512;
      #pragma unroll
      for (int m = 0; m < 4; ++m)
        #pragma unroll
        for (int n = 0; n < 8; ++n)
          acc[m][n] = __builtin_amdgcn_mfma_f32_16x16x32_bf16(af[m], bA[n], acc[m][n], 0,0,0);
      asm volatile("s_waitcnt vmcnt(8)" ::: "memory");
      __builtin_amdgcn_s_barrier();
    }
    // ---- odd step: read buf1, cur=bB; prefetch (t+1) -> buf0, bA ----
    {
      #pragma unroll
      for (int m = 0; m < 4; ++m) af[m] = *(const bf16x8*)&lds[4096 + aoff[m]];
      const bool pf = (t2 < NT/2 - 1);
      if (pf){
        gload_lds16(pA0, &lds[dA0]); pA0 += 32;
        gload_lds16(pA1, &lds[dA1]); pA1 += 32;
        #pragma unroll
        for (int n = 0; n < 8; ++n)
          bA[n] = *(const bf16x8*)(bB0 + (size_t)n*(NKT*512) + koff);
        koff += 512;
      }
      #pragma unroll
      for (int m = 0; m < 4; ++m)
        #pragma unroll
        for (int n = 0; n < 8; ++n)
          acc[m][n] = __builtin_amdgcn_mfma_f32_16x16x32_bf16(af[m], bB[n], acc[m][n], 0,0,0);
      if (pf) { asm volatile("s_waitcnt vmcnt(8)" ::: "memory"); }
      else    { asm volatile("s_waitcnt vmcnt(0)" ::: "memory"); }
      __builtin_amdgcn_s_barrier();
    }
  }

  // ---- epilogue: row = m0 + wr*64 + m*16 + hi*4 + i; col = n0 + wc*128 + n*16 + lr
  if (MODE == 0 && n0 < 2048){
    #pragma unroll
    for (int m = 0; m < 4; ++m){
      #pragma unroll
      for (int i = 0; i < 4; ++i){
        float p = 0.f;
        #pragma unroll
        for (int n = 0; n < 8; ++n) p += silu_f(acc[m][n][i]);
        p += __shfl_xor(p, 8); p += __shfl_xor(p, 4);
        p += __shfl_xor(p, 2); p += __shfl_xor(p, 1);
        if (lr == 0){
          int r = m0 + wr*64 + m*16 + (hi<<2) + i;
          atomicAdd(xraw + r, p);
        }
      }
    }
  } else if (MODE == 0){
    #pragma unroll
    for (int m = 0; m < 4; ++m){
      int rowb = m0 + wr*64 + m*16 + (hi<<2);
      #pragma unroll
      for (int n = 0; n < 8; ++n){
        int col = n0 + wc*128 + n*16 + lr;
        #pragma unroll
        for (int i = 0; i < 4; ++i){
          int r = rowb + i;
          float v = acc[m][n][i];
          if (col < 4096)      o_g[(size_t)r*LDG + (col-2048)] = (bf16_t)silu_f(v);
          else if (col < 4480) o_z[(size_t)r*384 + (col-4096)] = v;
        }
      }
    }
  } else {
    #pragma unroll
    for (int m = 0; m < 4; ++m){
      int rowb = m0 + wr*64 + m*16 + (hi<<2);
      #pragma unroll
      for (int i = 0; i < 4; ++i){
        int r = rowb + i;
        float s = scale[r];
        #pragma unroll
        for (int n = 0; n < 8; ++n){
          int col = n0 + wc*128 + n*16 + lr;
          atomicAdd(o_f + (size_t)r*DMODEL + col, acc[m][n][i]*s);
        }
      }
    }
  }
}

// ---------------- kernel 2: per-token fuse (RMS + scalars) ----------------
__global__ __launch_bounds__(128) void fuse_kernel(
    const float* __restrict__ xraw, const float* __restrict__ zs,
    const float* __restrict__ wnB, const float* __restrict__ wnC,
    const float* __restrict__ Bb, const float* __restrict__ Cb,
    const float* __restrict__ dtb, const float* __restrict__ Alog,
    float* __restrict__ Bn, float* __restrict__ Cn, float* __restrict__ dtth,
    float* __restrict__ dts, float* __restrict__ alphas, float* __restrict__ lams,
    float* __restrict__ xbar, float* Asum)
{
  __shared__ float red[128];
  int r = blockIdx.x, t = threadIdx.x;
  const float* zr = zs + (size_t)r*384;
  float bv = zr[t], cv = zr[128+t];
  float b2 = blockReduce128(bv*bv, red, t);
  float c2 = blockReduce128(cv*cv, red, t);
  float rb = rsqrtf(b2*(1.f/128.f) + EPSV);
  float rc = rsqrtf(c2*(1.f/128.f) + EPSV);
  Bn[(size_t)r*128 + t] = bv*rb*wnB[t] + Bb[t];
  Cn[(size_t)r*128 + t] = cv*rc*wnC[t] + Cb[t];

  float dt = softplus_f(zr[256] + dtb[0]);
  if (t < 64) dtth[(size_t)r*64 + t] = dt * zr[258+t];
  if (t == 0){
    float Av  = -softplus_f(zr[257] + Alog[0]);
    float lam = sigmoid_f(zr[322]);
    dts[r]    = dt;
    alphas[r] = expf(dt*Av);
    lams[r]   = lam;
    xbar[r]   = xraw[r] * (1.f/2048.f);
    atomicAdd(Asum, Av);
  }
}

// ---------------- kernel 3a: per-chunk angle sums ----------------
__global__ __launch_bounds__(64) void rope_sum_kernel(
    const float* __restrict__ dtth, float* __restrict__ csum)
{
  int b  = blockIdx.x >> 7;
  int ch = blockIdx.x & 127;
  int d  = threadIdx.x;
  const float* base = dtth + ((size_t)b*LSEQ + (size_t)ch*RCLEN)*64 + d;
  float s = 0.f;
  #pragma unroll
  for (int i = 0; i < RCLEN; ++i) s += base[(size_t)i*64];
  csum[((size_t)b*RCH + ch)*64 + d] = s;
}

// ---------------- kernel 3b: exclusive prefix over chunks (in place) -------
__global__ __launch_bounds__(64) void rope_prefix_kernel(float* __restrict__ csum)
{
  int b = blockIdx.x, d = threadIdx.x;
  float s = 0.f;
  for (int c = 0; c < RCH; ++c){
    size_t idx = ((size_t)b*RCH + c)*64 + d;
    float v = csum[idx]; csum[idx] = s; s += v;
  }
}

// ---------------- kernel 3c: rope apply with chunk offsets ----------------
__global__ __launch_bounds__(64) void rope_apply_kernel(
    const float* __restrict__ dtth, const float* __restrict__ csum,
    float* __restrict__ Bn, float* __restrict__ Cn)
{
  int b  = blockIdx.x >> 7;
  int ch = blockIdx.x & 127;
  int d  = threadIdx.x;
  float ca = csum[((size_t)b*RCH + ch)*64 + d];
  int l0 = ch*RCLEN;
  const float* base = dtth + ((size_t)b*LSEQ)*64 + d;
  for (int l = l0; l < l0 + RCLEN; ++l){
    ca += base[(size_t)l*64];
    float sn, cs;
    sincosf(ca, &sn, &cs);
    size_t ro = ((size_t)b*LSEQ + l)*128;
    float b1 = Bn[ro+d], b2v = Bn[ro+64+d];
    Bn[ro+d]    = b1*cs - b2v*sn;
    Bn[ro+64+d] = b1*sn + b2v*cs;
    float c1 = Cn[ro+d], c2v = Cn[ro+64+d];
    Cn[ro+d]    = c1*cs - c2v*sn;
    Cn[ro+64+d] = c1*sn + c2v*cs;
  }
}

// ---------------- kernel 4a: chunk-local scan ----------------
__global__ __launch_bounds__(64) void scan_local_kernel(
    const float* __restrict__ dts, const float* __restrict__ alphas,
    const float* __restrict__ lams, const float* __restrict__ xbar,
    const float* __restrict__ Asum,
    const float* __restrict__ Bn, const float* __restrict__ Cn,
    float* __restrict__ ylocal, float* __restrict__ Pfix,
    float* __restrict__ Sfin, float* __restrict__ Dch)
{
  int b  = blockIdx.x / SCHUNK;
  int ch = blockIdx.x % SCHUNK;
  int n  = threadIdx.x;
  float Abar = Asum[0] * (1.f/(float)ROWS);
  float s1 = 0.f, s2 = 0.f, P = 1.f;
  int l0 = ch*SCLEN;
  #pragma unroll
  for (int i = 0; i < SCLEN; ++i){
    int l = l0 + i;
    size_t r = (size_t)b*LSEQ + l;
    float dt = dts[r], lam = lams[r], al = alphas[r], xb = xbar[r];
    float xp = (l > 0) ? xbar[r-1] : 0.f;
    float um = lam*xb + (1.f-lam)*al*xp;
    float dA = expf(dt*Abar);
    float coef = dt*um;
    size_t ro = r*128;
    s1 = dA*s1 + coef*Bn[ro+n];
    s2 = dA*s2 + coef*Bn[ro+64+n];
    P *= dA;
    float p = s1*Cn[ro+n] + s2*Cn[ro+64+n];
    #pragma unroll
    for (int off = 32; off > 0; off >>= 1) p += __shfl_down(p, off);
    if (n == 0){ ylocal[r] = p; Pfix[r] = P; }
  }
  size_t so = ((size_t)b*SCHUNK + ch)*128;
  Sfin[so + n]      = s1;
  Sfin[so + 64 + n] = s2;
  if (n == 0) Dch[b*SCHUNK + ch] = P;
}

// ---------------- kernel 4b: inter-chunk carry ----------------
__global__ __launch_bounds__(128) void scan_carry_kernel(
    const float* __restrict__ Sfin, const float* __restrict__ Dch,
    float* __restrict__ Sin)
{
  int b = blockIdx.x;
  int n = threadIdx.x;
  float s = 0.f;
  for (int c = 0; c < SCHUNK; ++c){
    size_t so = ((size_t)b*SCHUNK + c)*128;
    Sin[so + n] = s;
    s = Dch[b*SCHUNK + c]*s + Sfin[so + n];
  }
}

// ---------------- kernel 4c: fixup ----------------
__global__ __launch_bounds__(256) void scan_fix_kernel(
    const float* __restrict__ Cn, const float* __restrict__ Sin,
    const float* __restrict__ ylocal, const float* __restrict__ Pfix,
    float* __restrict__ outsv)
{
  int r = blockIdx.x*4 + (threadIdx.x>>6);
  int n = threadIdx.x & 63;
  int b  = r / LSEQ;
  int ch = (r % LSEQ) / SCLEN;
  const float* si = Sin + ((size_t)b*SCHUNK + ch)*128;
  size_t ro = (size_t)r*128;
  float p = Cn[ro+n]*si[n] + Cn[ro+64+n]*si[64+n];
  #pragma unroll
  for (int off = 32; off > 0; off >>= 1) p += __shfl_down(p, off);
  if (n == 0) outsv[r] = ylocal[r] + Pfix[r]*p;
}

// ---------------- launch ----------------
extern "C" void kernel_launch(void* const* d_in, const int* in_sizes, int n_in,
                              void* d_out, int out_size, void* d_ws, size_t ws_size,
                              hipStream_t stream)
{
  const float* u    = (const float*)d_in[0];
  const float* W_in = (const float*)d_in[1];
  const float* wnB  = (const float*)d_in[2];
  const float* wnC  = (const float*)d_in[3];
  const float* Bb   = (const float*)d_in[4];
  const float* Cb   = (const float*)d_in[5];
  const float* dtb  = (const float*)d_in[6];
  const float* Alog = (const float*)d_in[7];
  const float* Wout = (const float*)d_in[8];
  float* out = (float*)d_out;
  char* ws = (char*)d_ws;

  constexpr size_t OFF_ASUM = 0;
  constexpr size_t OFF_UBF  = 256;
  constexpr size_t SZ_UBF   = (size_t)ROWS*LDU*2;
  constexpr size_t OFF_WIN  = OFF_UBF + SZ_UBF;     // WinSh (ZPAD*1024 elems)
  constexpr size_t SZ_WIN   = (size_t)ZPAD*LDU*2;
  constexpr size_t OFF_WOUT = OFF_WIN + SZ_WIN;     // WoutSh (DMODEL*EDIM elems)
  constexpr size_t SZ_WOUT  = (size_t)DMODEL*LDG*2;
  constexpr size_t OFF_G    = OFF_WOUT + SZ_WOUT;
  constexpr size_t SZ_G     = (size_t)ROWS*LDG*2;
  constexpr size_t OFF_ZS   = OFF_G + SZ_G;
  constexpr size_t SZ_ZS    = (size_t)ROWS*384*4;
  constexpr size_t OFF_BN   = OFF_ZS + SZ_ZS;
  constexpr size_t SZ_BN    = (size_t)ROWS*128*4;
  constexpr size_t OFF_CN   = OFF_BN + SZ_BN;
  constexpr size_t OFF_DTTH = OFF_CN + SZ_BN;
  constexpr size_t SZ_DTTH  = (size_t)ROWS*64*4;
  constexpr size_t OFF_XRAW = OFF_DTTH + SZ_DTTH;
  constexpr size_t OFF_DT   = OFF_XRAW + (size_t)ROWS*4;
  constexpr size_t OFF_AL   = OFF_DT  + (size_t)ROWS*4;
  constexpr size_t OFF_LAM  = OFF_AL  + (size_t)ROWS*4;
  constexpr size_t OFF_XB   = OFF_LAM + (size_t)ROWS*4;
  constexpr size_t OFF_OUTS = OFF_XB  + (size_t)ROWS*4;
  constexpr size_t OFF_YLOC = OFF_OUTS + (size_t)ROWS*4;
  constexpr size_t OFF_PFIX = OFF_YLOC + (size_t)ROWS*4;
  constexpr size_t OFF_SFIN = OFF_PFIX + (size_t)ROWS*4;
  constexpr size_t SZ_SFIN  = (size_t)B_SZ*SCHUNK*128*4;
  constexpr size_t OFF_DCH  = OFF_SFIN + SZ_SFIN;
  constexpr size_t OFF_SIN  = OFF_DCH + (size_t)B_SZ*SCHUNK*4;
  constexpr size_t OFF_CSUM = OFF_SIN + SZ_SFIN;

  float*  Asum   = (float*) (ws + OFF_ASUM);
  bf16_t* ubf    = (bf16_t*)(ws + OFF_UBF);
  bf16_t* winSh  = (bf16_t*)(ws + OFF_WIN);
  bf16_t* woutSh = (bf16_t*)(ws + OFF_WOUT);
  bf16_t* gbuf   = (bf16_t*)(ws + OFF_G);
  float*  zsb    = (float*) (ws + OFF_ZS);
  float*  Bn     = (float*) (ws + OFF_BN);
  float*  Cn     = (float*) (ws + OFF_CN);
  float*  dtth   = (float*) (ws + OFF_DTTH);
  float*  xraw   = (float*) (ws + OFF_XRAW);
  float*  dts    = (float*) (ws + OFF_DT);
  float*  alphas = (float*) (ws + OFF_AL);
  float*  lams   = (float*) (ws + OFF_LAM);
  float*  xbar   = (float*) (ws + OFF_XB);
  float*  outsv  = (float*) (ws + OFF_OUTS);
  float*  ylocal = (float*) (ws + OFF_YLOC);
  float*  Pfix   = (float*) (ws + OFF_PFIX);
  float*  Sfin   = (float*) (ws + OFF_SFIN);
  float*  Dch    = (float*) (ws + OFF_DCH);
  float*  Sin    = (float*) (ws + OFF_SIN);
  float*  csum   = (float*) (ws + OFF_CSUM);

  {
    size_t total4 = ((size_t)ROWS*DMODEL + (size_t)ZPAD*DMODEL + (size_t)DMODEL*EDIM)/4;
    int blocks = (int)((total4 + 255)/256);
    prep_kernel<<<blocks, 256, 0, stream>>>(
        (const float4*)u, (const float4*)W_in, (const float4*)Wout,
        ubf, winSh, woutSh, Asum, xraw);
  }
  hipMemsetAsync(out, 0, (size_t)ROWS*DMODEL*sizeof(float), stream);

  // GEMM1: 128x256 tiles, A=ubf (DMA), B=WinSh (direct frags). 1152 blocks.
  gemmV_kernel<LDU, 32, 32, ZPAD/256, 0>
      <<<(ZPAD/256)*(ROWS/128), 256, 0, stream>>>(
      ubf, winSh, xraw, gbuf, zsb, nullptr, nullptr);
  fuse_kernel<<<ROWS, 128, 0, stream>>>(xraw, zsb, wnB, wnC, Bb, Cb, dtb, Alog,
                                        Bn, Cn, dtth, dts, alphas, lams, xbar, Asum);
  rope_sum_kernel<<<B_SZ*RCH, 64, 0, stream>>>(dtth, csum);
  rope_prefix_kernel<<<B_SZ, 64, 0, stream>>>(csum);
  rope_apply_kernel<<<B_SZ*RCH, 64, 0, stream>>>(dtth, csum, Bn, Cn);
  scan_local_kernel<<<B_SZ*SCHUNK, 64, 0, stream>>>(dts, alphas, lams, xbar, Asum,
                                                    Bn, Cn, ylocal, Pfix, Sfin, Dch);
  scan_carry_kernel<<<B_SZ, 128, 0, stream>>>(Sfin, Dch, Sin);
  scan_fix_kernel<<<ROWS/4, 256, 0, stream>>>(Cn, Sin, ylocal, Pfix, outsv);
  // GEMM2: split-K x2 (K=1024 each), A=gbuf, B=WoutSh. 512 blocks, 2/CU.
  gemmV_kernel<LDG, 64, 32, DMODEL/256, 1>
      <<<2*(DMODEL/256)*(ROWS/128), 256, 0, stream>>>(
      gbuf, woutSh, nullptr, nullptr, nullptr, outsv, out);
}

// Round 13
// 342.838 us; speedup vs baseline: 1.6135x; 1.1143x over previous
//
#include <hip/hip_runtime.h>
#include <cstdint>
#include <cstddef>

typedef __bf16 bf16_t;
typedef bf16_t bf16x8 __attribute__((ext_vector_type(8)));
typedef bf16_t bf16x4 __attribute__((ext_vector_type(4)));
typedef float f32x4 __attribute__((ext_vector_type(4)));

#define B_SZ    4
#define LSEQ    2048
#define DMODEL  1024
#define EDIM    2048
#define ZDIM    4419
#define ZPAD    4608
#define ROWS    (B_SZ*LSEQ)     /* 8192 */
#define EPSV    1e-5f

/* padded leading dims for row-major A operands */
#define LDU     1088
#define LDG     2112

#define SCHUNK  128
#define SCLEN   (LSEQ/SCHUNK)   /* 16 */
#define RCH     128
#define RCLEN   (LSEQ/RCH)      /* 16 */

// ---------------- helpers ----------------
__device__ __forceinline__ float softplus_f(float x){
  return fmaxf(x, 0.f) + log1pf(expf(-fabsf(x)));
}
__device__ __forceinline__ float sigmoid_f(float x){ return 1.f/(1.f+expf(-x)); }
__device__ __forceinline__ float silu_f(float x){ return x/(1.f+expf(-x)); }

__device__ __forceinline__ void gload_lds16(const void* g, void* l){
  __builtin_amdgcn_global_load_lds(
      (const __attribute__((address_space(1))) void*)g,
      (__attribute__((address_space(3))) void*)l, 16, 0, 0);
}

__device__ __forceinline__ float blockReduce128(float v, float* red, int t){
  red[t] = v; __syncthreads();
  #pragma unroll
  for (int off = 64; off > 0; off >>= 1){
    if (t < off) red[t] += red[t+off];
    __syncthreads();
  }
  float r = red[0];
  __syncthreads();
  return r;
}

// ---------------- kernel 0: casts; W -> fragment-linear shuffled layout ----
__global__ __launch_bounds__(256) void prep_kernel(
    const float4* __restrict__ u4, const float4* __restrict__ win4,
    const float4* __restrict__ wout4,
    bf16_t* __restrict__ ubf, bf16_t* __restrict__ winSh, bf16_t* __restrict__ woutSh,
    float* __restrict__ Asum, float* __restrict__ xraw)
{
  size_t i = (size_t)blockIdx.x*256 + threadIdx.x;
  if (i == 0) Asum[0] = 0.f;
  if (i < ROWS) xraw[i] = 0.f;
  const size_t NU4 = (size_t)ROWS*DMODEL/4;
  const size_t NW4 = (size_t)ZPAD*DMODEL/4;
  const size_t NO4 = (size_t)DMODEL*EDIM/4;
  if (i < NU4){
    float4 v = u4[i];
    size_t e = i*4, row = e>>10, col = e&1023;
    bf16x4 o = { (bf16_t)v.x, (bf16_t)v.y, (bf16_t)v.z, (bf16_t)v.w };
    *(bf16x4*)&ubf[row*LDU + col] = o;
    return;
  }
  i -= NU4;
  if (i < NW4){
    size_t e = i*4, row = e>>10, k = e&1023;
    bf16x4 o;
    if (row < (size_t)ZDIM){
      float4 v = win4[i];
      o = bf16x4{ (bf16_t)v.x, (bf16_t)v.y, (bf16_t)v.z, (bf16_t)v.w };
    } else {
      o = bf16x4{ (bf16_t)0.f, (bf16_t)0.f, (bf16_t)0.f, (bf16_t)0.f };
    }
    int ntile = (int)(row>>4), colf = (int)(row&15);
    int kt = (int)(k>>5), koct = (int)((k>>3)&3), ko = (int)(k&7);
    size_t off = (((size_t)ntile*32 + kt)<<9) + (koct<<7) + (colf<<3) + ko;
    *(bf16x4*)&winSh[off] = o;
    return;
  }
  i -= NW4;
  if (i < NO4){
    float4 v = wout4[i];
    size_t e = i*4, row = e>>11, k = e&2047;
    bf16x4 o = { (bf16_t)v.x, (bf16_t)v.y, (bf16_t)v.z, (bf16_t)v.w };
    int ntile = (int)(row>>4), colf = (int)(row&15);
    int kt = (int)(k>>5), koct = (int)((k>>3)&3), ko = (int)(k&7);
    size_t off = (((size_t)ntile*64 + kt)<<9) + (koct<<7) + (colf<<3) + ko;
    *(bf16x4*)&woutSh[off] = o;
  }
}

// -------- GEMM-V: A via LDS-DMA (8KB/step), B direct global->VGPR ---------
// (R12-verified structure; MODE 1 now single-K, plain scaled stores.)
template<int LDA_, int NKT, int NT, int NXT, int MODE>
__global__ __launch_bounds__(256, 2) void gemmV_kernel(
    const bf16_t* __restrict__ A0, const bf16_t* __restrict__ Bsh,
    float* __restrict__ xraw, bf16_t* __restrict__ o_g, float* __restrict__ o_z,
    const float* __restrict__ scale, float* __restrict__ o_f)
{
  __shared__ __align__(16) bf16_t lds[8192];   // two 4096-elem A buffers

  const int tid = threadIdx.x;
  const int wid = tid>>6, lane = tid&63;
  const int wr = wid>>1, wc = wid&1;
  const int lr = lane&15, hi = lane>>4;

  constexpr int MB = ROWS/128;                 // 64
  constexpr int NWG = NXT*MB;
  const int id = blockIdx.x;
  const int rid = (id & 7)*(NWG/8) + (id>>3);  // bijective (NWG%8==0)
  const int bx = rid % NXT, by = rid / NXT;
  const int m0 = by*128, n0 = bx*256;

  f32x4 acc[4][8] = {};

  // ---- A staging pointers (rotation swizzle, source-side) ----
  const bf16_t* pA0; const bf16_t* pA1;
  int dA0, dA1;
  {
    int c0 = tid,      r0 = c0>>2, d0 = c0&3, g0 = (d0 - (r0>>1)) & 3;
    int c1 = 256+tid,  r1 = c1>>2, d1 = c1&3, g1 = (d1 - (r1>>1)) & 3;
    pA0 = A0 + (size_t)(m0+r0)*LDA_ + g0*8;
    pA1 = A0 + (size_t)(m0+r1)*LDA_ + g1*8;
    dA0 = c0*8; dA1 = c1*8;
  }
  // ---- A read offsets (read-side rotation) ----
  int aoff[4];
  {
    int R0 = wr*64 + lr;
    int cA = (hi + (R0>>1)) & 3;
    #pragma unroll
    for (int m = 0; m < 4; ++m) aoff[m] = (R0 + 16*m)*32 + cA*8;
  }
  // ---- B fragment base (per-lane, coalesced 1KB per frag) ----
  const bf16_t* bB0 = Bsh + (((size_t)((n0>>4) + wc*8)*NKT)<<9) + lane*8;
  int koff = 0;

  bf16x8 bA[8], bB[8], af[4];

  // ---- prologue: stage A(t0) -> buf0; load B(t0) ----
  gload_lds16(pA0, &lds[dA0]); pA0 += 32;
  gload_lds16(pA1, &lds[dA1]); pA1 += 32;
  #pragma unroll
  for (int n = 0; n < 8; ++n)
    bA[n] = *(const bf16x8*)(bB0 + (size_t)n*(NKT*512) + koff);
  koff += 512;
  asm volatile("s_waitcnt vmcnt(8)" ::: "memory");
  __builtin_amdgcn_s_barrier();

  #pragma unroll 1
  for (int t2 = 0; t2 < NT/2; ++t2){
    // ---- even step ----
    {
      #pragma unroll
      for (int m = 0; m < 4; ++m) af[m] = *(const bf16x8*)&lds[aoff[m]];
      gload_lds16(pA0, &lds[4096 + dA0]); pA0 += 32;
      gload_lds16(pA1, &lds[4096 + dA1]); pA1 += 32;
      #pragma unroll
      for (int n = 0; n < 8; ++n)
        bB[n] = *(const bf16x8*)(bB0 + (size_t)n*(NKT*512) + koff);
      koff += 512;
      #pragma unroll
      for (int m = 0; m < 4; ++m)
        #pragma unroll
        for (int n = 0; n < 8; ++n)
          acc[m][n] = __builtin_amdgcn_mfma_f32_16x16x32_bf16(af[m], bA[n], acc[m][n], 0,0,0);
      asm volatile("s_waitcnt vmcnt(8)" ::: "memory");
      __builtin_amdgcn_s_barrier();
    }
    // ---- odd step ----
    {
      #pragma unroll
      for (int m = 0; m < 4; ++m) af[m] = *(const bf16x8*)&lds[4096 + aoff[m]];
      const bool pf = (t2 < NT/2 - 1);
      if (pf){
        gload_lds16(pA0, &lds[dA0]); pA0 += 32;
        gload_lds16(pA1, &lds[dA1]); pA1 += 32;
        #pragma unroll
        for (int n = 0; n < 8; ++n)
          bA[n] = *(const bf16x8*)(bB0 + (size_t)n*(NKT*512) + koff);
        koff += 512;
      }
      #pragma unroll
      for (int m = 0; m < 4; ++m)
        #pragma unroll
        for (int n = 0; n < 8; ++n)
          acc[m][n] = __builtin_amdgcn_mfma_f32_16x16x32_bf16(af[m], bB[n], acc[m][n], 0,0,0);
      if (pf) { asm volatile("s_waitcnt vmcnt(8)" ::: "memory"); }
      else    { asm volatile("s_waitcnt vmcnt(0)" ::: "memory"); }
      __builtin_amdgcn_s_barrier();
    }
  }

  // ---- epilogue: row = m0 + wr*64 + m*16 + hi*4 + i; col = n0 + wc*128 + n*16 + lr
  if (MODE == 0 && n0 < 2048){
    #pragma unroll
    for (int m = 0; m < 4; ++m){
      #pragma unroll
      for (int i = 0; i < 4; ++i){
        float p = 0.f;
        #pragma unroll
        for (int n = 0; n < 8; ++n) p += silu_f(acc[m][n][i]);
        p += __shfl_xor(p, 8); p += __shfl_xor(p, 4);
        p += __shfl_xor(p, 2); p += __shfl_xor(p, 1);
        if (lr == 0){
          int r = m0 + wr*64 + m*16 + (hi<<2) + i;
          atomicAdd(xraw + r, p);
        }
      }
    }
  } else if (MODE == 0){
    #pragma unroll
    for (int m = 0; m < 4; ++m){
      int rowb = m0 + wr*64 + m*16 + (hi<<2);
      #pragma unroll
      for (int n = 0; n < 8; ++n){
        int col = n0 + wc*128 + n*16 + lr;
        #pragma unroll
        for (int i = 0; i < 4; ++i){
          int r = rowb + i;
          float v = acc[m][n][i];
          if (col < 4096)      o_g[(size_t)r*LDG + (col-2048)] = (bf16_t)silu_f(v);
          else if (col < 4480) o_z[(size_t)r*384 + (col-4096)] = v;
        }
      }
    }
  } else {
    #pragma unroll
    for (int m = 0; m < 4; ++m){
      int rowb = m0 + wr*64 + m*16 + (hi<<2);
      #pragma unroll
      for (int i = 0; i < 4; ++i){
        int r = rowb + i;
        float s = scale[r];
        #pragma unroll
        for (int n = 0; n < 8; ++n){
          int col = n0 + wc*128 + n*16 + lr;
          o_f[(size_t)r*DMODEL + col] = acc[m][n][i]*s;
        }
      }
    }
  }
}

// ---------------- kernel 2: per-token fuse (RMS + scalars) ----------------
__global__ __launch_bounds__(128) void fuse_kernel(
    const float* __restrict__ xraw, const float* __restrict__ zs,
    const float* __restrict__ wnB, const float* __restrict__ wnC,
    const float* __restrict__ Bb, const float* __restrict__ Cb,
    const float* __restrict__ dtb, const float* __restrict__ Alog,
    float* __restrict__ Bn, float* __restrict__ Cn, float* __restrict__ dtth,
    float* __restrict__ dts, float* __restrict__ alphas, float* __restrict__ lams,
    float* __restrict__ xbar, float* Asum)
{
  __shared__ float red[128];
  int r = blockIdx.x, t = threadIdx.x;
  const float* zr = zs + (size_t)r*384;
  float bv = zr[t], cv = zr[128+t];
  float b2 = blockReduce128(bv*bv, red, t);
  float c2 = blockReduce128(cv*cv, red, t);
  float rb = rsqrtf(b2*(1.f/128.f) + EPSV);
  float rc = rsqrtf(c2*(1.f/128.f) + EPSV);
  Bn[(size_t)r*128 + t] = bv*rb*wnB[t] + Bb[t];
  Cn[(size_t)r*128 + t] = cv*rc*wnC[t] + Cb[t];

  float dt = softplus_f(zr[256] + dtb[0]);
  if (t < 64) dtth[(size_t)r*64 + t] = dt * zr[258+t];
  if (t == 0){
    float Av  = -softplus_f(zr[257] + Alog[0]);
    float lam = sigmoid_f(zr[322]);
    dts[r]    = dt;
    alphas[r] = expf(dt*Av);
    lams[r]   = lam;
    xbar[r]   = xraw[r] * (1.f/2048.f);
    atomicAdd(Asum, Av);
  }
}

// ---------------- kernel 3a: per-chunk angle sums ----------------
__global__ __launch_bounds__(64) void rope_sum_kernel(
    const float* __restrict__ dtth, float* __restrict__ csum)
{
  int b  = blockIdx.x >> 7;
  int ch = blockIdx.x & 127;
  int d  = threadIdx.x;
  const float* base = dtth + ((size_t)b*LSEQ + (size_t)ch*RCLEN)*64 + d;
  float s = 0.f;
  #pragma unroll
  for (int i = 0; i < RCLEN; ++i) s += base[(size_t)i*64];
  csum[((size_t)b*RCH + ch)*64 + d] = s;
}

// ---------------- kernel 3b: exclusive prefix over chunks (in place) -------
__global__ __launch_bounds__(64) void rope_prefix_kernel(float* __restrict__ csum)
{
  int b = blockIdx.x, d = threadIdx.x;
  float s = 0.f;
  for (int c = 0; c < RCH; ++c){
    size_t idx = ((size_t)b*RCH + c)*64 + d;
    float v = csum[idx]; csum[idx] = s; s += v;
  }
}

// ------- kernel 3c+4a merged: rope (in-register) + chunk-local scan -------
// Block (b, ch): 64 threads, 16 tokens. Thread d handles rope dims (d, d+64)
// and scan states (d, d+64). Bn rope'd in-register only (never written);
// Cn rope'd and written back (scan_fix needs it).
__global__ __launch_bounds__(64) void rope_scan_kernel(
    const float* __restrict__ dtth, const float* __restrict__ csum,
    const float* __restrict__ dts, const float* __restrict__ alphas,
    const float* __restrict__ lams, const float* __restrict__ xbar,
    const float* __restrict__ Asum,
    const float* __restrict__ Bn, float* __restrict__ Cn,
    float* __restrict__ ylocal, float* __restrict__ Pfix,
    float* __restrict__ Sfin, float* __restrict__ Dch)
{
  int b  = blockIdx.x >> 7;
  int ch = blockIdx.x & 127;
  int d  = threadIdx.x;
  float Abar = Asum[0] * (1.f/(float)ROWS);
  float ca = csum[((size_t)b*RCH + ch)*64 + d];
  float s1 = 0.f, s2 = 0.f, P = 1.f;
  int l0 = ch*SCLEN;
  #pragma unroll
  for (int i = 0; i < SCLEN; ++i){
    int l = l0 + i;
    size_t r = (size_t)b*LSEQ + l;
    ca += dtth[r*64 + d];
    float sn, cs;
    sincosf(ca, &sn, &cs);
    size_t ro = r*128;
    float b1 = Bn[ro+d], b2v = Bn[ro+64+d];
    float rb1 = b1*cs - b2v*sn;
    float rb2 = b1*sn + b2v*cs;
    float c1 = Cn[ro+d], c2v = Cn[ro+64+d];
    float rc1 = c1*cs - c2v*sn;
    float rc2 = c1*sn + c2v*cs;
    Cn[ro+d]    = rc1;
    Cn[ro+64+d] = rc2;

    float dt = dts[r], lam = lams[r], al = alphas[r], xb = xbar[r];
    float xp = (l > 0) ? xbar[r-1] : 0.f;
    float um = lam*xb + (1.f-lam)*al*xp;
    float dA = expf(dt*Abar);
    float coef = dt*um;
    s1 = dA*s1 + coef*rb1;
    s2 = dA*s2 + coef*rb2;
    P *= dA;
    float p = s1*rc1 + s2*rc2;
    #pragma unroll
    for (int off = 32; off > 0; off >>= 1) p += __shfl_down(p, off);
    if (d == 0){ ylocal[r] = p; Pfix[r] = P; }
  }
  size_t so = ((size_t)b*SCHUNK + ch)*128;
  Sfin[so + d]      = s1;
  Sfin[so + 64 + d] = s2;
  if (d == 0) Dch[b*SCHUNK + ch] = P;
}

// ---------------- kernel 4b: inter-chunk carry ----------------
__global__ __launch_bounds__(128) void scan_carry_kernel(
    const float* __restrict__ Sfin, const float* __restrict__ Dch,
    float* __restrict__ Sin)
{
  int b = blockIdx.x;
  int n = threadIdx.x;
  float s = 0.f;
  for (int c = 0; c < SCHUNK; ++c){
    size_t so = ((size_t)b*SCHUNK + c)*128;
    Sin[so + n] = s;
    s = Dch[b*SCHUNK + c]*s + Sfin[so + n];
  }
}

// ---------------- kernel 4c: fixup ----------------
__global__ __launch_bounds__(256) void scan_fix_kernel(
    const float* __restrict__ Cn, const float* __restrict__ Sin,
    const float* __restrict__ ylocal, const float* __restrict__ Pfix,
    float* __restrict__ outsv)
{
  int r = blockIdx.x*4 + (threadIdx.x>>6);
  int n = threadIdx.x & 63;
  int b  = r / LSEQ;
  int ch = (r % LSEQ) / SCLEN;
  const float* si = Sin + ((size_t)b*SCHUNK + ch)*128;
  size_t ro = (size_t)r*128;
  float p = Cn[ro+n]*si[n] + Cn[ro+64+n]*si[64+n];
  #pragma unroll
  for (int off = 32; off > 0; off >>= 1) p += __shfl_down(p, off);
  if (n == 0) outsv[r] = ylocal[r] + Pfix[r]*p;
}

// ---------------- launch ----------------
extern "C" void kernel_launch(void* const* d_in, const int* in_sizes, int n_in,
                              void* d_out, int out_size, void* d_ws, size_t ws_size,
                              hipStream_t stream)
{
  const float* u    = (const float*)d_in[0];
  const float* W_in = (const float*)d_in[1];
  const float* wnB  = (const float*)d_in[2];
  const float* wnC  = (const float*)d_in[3];
  const float* Bb   = (const float*)d_in[4];
  const float* Cb   = (const float*)d_in[5];
  const float* dtb  = (const float*)d_in[6];
  const float* Alog = (const float*)d_in[7];
  const float* Wout = (const float*)d_in[8];
  float* out = (float*)d_out;
  char* ws = (char*)d_ws;

  constexpr size_t OFF_ASUM = 0;
  constexpr size_t OFF_UBF  = 256;
  constexpr size_t SZ_UBF   = (size_t)ROWS*LDU*2;
  constexpr size_t OFF_WIN  = OFF_UBF + SZ_UBF;
  constexpr size_t SZ_WIN   = (size_t)ZPAD*LDU*2;
  constexpr size_t OFF_WOUT = OFF_WIN + SZ_WIN;
  constexpr size_t SZ_WOUT  = (size_t)DMODEL*LDG*2;
  constexpr size_t OFF_G    = OFF_WOUT + SZ_WOUT;
  constexpr size_t SZ_G     = (size_t)ROWS*LDG*2;
  constexpr size_t OFF_ZS   = OFF_G + SZ_G;
  constexpr size_t SZ_ZS    = (size_t)ROWS*384*4;
  constexpr size_t OFF_BN   = OFF_ZS + SZ_ZS;
  constexpr size_t SZ_BN    = (size_t)ROWS*128*4;
  constexpr size_t OFF_CN   = OFF_BN + SZ_BN;
  constexpr size_t OFF_DTTH = OFF_CN + SZ_BN;
  constexpr size_t SZ_DTTH  = (size_t)ROWS*64*4;
  constexpr size_t OFF_XRAW = OFF_DTTH + SZ_DTTH;
  constexpr size_t OFF_DT   = OFF_XRAW + (size_t)ROWS*4;
  constexpr size_t OFF_AL   = OFF_DT  + (size_t)ROWS*4;
  constexpr size_t OFF_LAM  = OFF_AL  + (size_t)ROWS*4;
  constexpr size_t OFF_XB   = OFF_LAM + (size_t)ROWS*4;
  constexpr size_t OFF_OUTS = OFF_XB  + (size_t)ROWS*4;
  constexpr size_t OFF_YLOC = OFF_OUTS + (size_t)ROWS*4;
  constexpr size_t OFF_PFIX = OFF_YLOC + (size_t)ROWS*4;
  constexpr size_t OFF_SFIN = OFF_PFIX + (size_t)ROWS*4;
  constexpr size_t SZ_SFIN  = (size_t)B_SZ*SCHUNK*128*4;
  constexpr size_t OFF_DCH  = OFF_SFIN + SZ_SFIN;
  constexpr size_t OFF_SIN  = OFF_DCH + (size_t)B_SZ*SCHUNK*4;
  constexpr size_t OFF_CSUM = OFF_SIN + SZ_SFIN;

  float*  Asum   = (float*) (ws + OFF_ASUM);
  bf16_t* ubf    = (bf16_t*)(ws + OFF_UBF);
  bf16_t* winSh  = (bf16_t*)(ws + OFF_WIN);
  bf16_t* woutSh = (bf16_t*)(ws + OFF_WOUT);
  bf16_t* gbuf   = (bf16_t*)(ws + OFF_G);
  float*  zsb    = (float*) (ws + OFF_ZS);
  float*  Bn     = (float*) (ws + OFF_BN);
  float*  Cn     = (float*) (ws + OFF_CN);
  float*  dtth   = (float*) (ws + OFF_DTTH);
  float*  xraw   = (float*) (ws + OFF_XRAW);
  float*  dts    = (float*) (ws + OFF_DT);
  float*  alphas = (float*) (ws + OFF_AL);
  float*  lams   = (float*) (ws + OFF_LAM);
  float*  xbar   = (float*) (ws + OFF_XB);
  float*  outsv  = (float*) (ws + OFF_OUTS);
  float*  ylocal = (float*) (ws + OFF_YLOC);
  float*  Pfix   = (float*) (ws + OFF_PFIX);
  float*  Sfin   = (float*) (ws + OFF_SFIN);
  float*  Dch    = (float*) (ws + OFF_DCH);
  float*  Sin    = (float*) (ws + OFF_SIN);
  float*  csum   = (float*) (ws + OFF_CSUM);

  {
    size_t total4 = ((size_t)ROWS*DMODEL + (size_t)ZPAD*DMODEL + (size_t)DMODEL*EDIM)/4;
    int blocks = (int)((total4 + 255)/256);
    prep_kernel<<<blocks, 256, 0, stream>>>(
        (const float4*)u, (const float4*)W_in, (const float4*)Wout,
        ubf, winSh, woutSh, Asum, xraw);
  }

  // GEMM1: 128x256 tiles, A=ubf (DMA), B=WinSh (direct frags). 1152 blocks.
  gemmV_kernel<LDU, 32, 32, ZPAD/256, 0>
      <<<(ZPAD/256)*(ROWS/128), 256, 0, stream>>>(
      ubf, winSh, xraw, gbuf, zsb, nullptr, nullptr);
  fuse_kernel<<<ROWS, 128, 0, stream>>>(xraw, zsb, wnB, wnC, Bb, Cb, dtb, Alog,
                                        Bn, Cn, dtth, dts, alphas, lams, xbar, Asum);
  rope_sum_kernel<<<B_SZ*RCH, 64, 0, stream>>>(dtth, csum);
  rope_prefix_kernel<<<B_SZ, 64, 0, stream>>>(csum);
  rope_scan_kernel<<<B_SZ*RCH, 64, 0, stream>>>(dtth, csum, dts, alphas, lams,
                                                xbar, Asum, Bn, Cn,
                                                ylocal, Pfix, Sfin, Dch);
  scan_carry_kernel<<<B_SZ, 128, 0, stream>>>(Sfin, Dch, Sin);
  scan_fix_kernel<<<ROWS/4, 256, 0, stream>>>(Cn, Sin, ylocal, Pfix, outsv);
  // GEMM2: single-K (K=2048, NT=64), plain scaled stores. 256 blocks.
  gemmV_kernel<LDG, 64, 64, DMODEL/256, 1>
      <<<(DMODEL/256)*(ROWS/128), 256, 0, stream>>>(
      gbuf, woutSh, nullptr, nullptr, nullptr, outsv, out);
}

// Round 14
// 337.567 us; speedup vs baseline: 1.6387x; 1.0156x over previous
//
#include <hip/hip_runtime.h>
#include <cstdint>
#include <cstddef>

typedef __bf16 bf16_t;
typedef bf16_t bf16x8 __attribute__((ext_vector_type(8)));
typedef bf16_t bf16x4 __attribute__((ext_vector_type(4)));
typedef float f32x4 __attribute__((ext_vector_type(4)));

#define B_SZ    4
#define LSEQ    2048
#define DMODEL  1024
#define EDIM    2048
#define ZDIM    4419
#define ZPAD    4608
#define ROWS    (B_SZ*LSEQ)     /* 8192 */
#define EPSV    1e-5f

/* padded leading dims for row-major A operands (GEMM2 path) */
#define LDU     1088
#define LDG     2112

#define SCHUNK  128
#define SCLEN   (LSEQ/SCHUNK)   /* 16 */
#define RCH     128
#define RCLEN   (LSEQ/RCH)      /* 16 */

// ---------------- helpers ----------------
__device__ __forceinline__ float softplus_f(float x){
  return fmaxf(x, 0.f) + log1pf(expf(-fabsf(x)));
}
__device__ __forceinline__ float sigmoid_f(float x){ return 1.f/(1.f+expf(-x)); }
__device__ __forceinline__ float silu_f(float x){ return x/(1.f+expf(-x)); }

__device__ __forceinline__ void gload_lds16(const void* g, void* l){
  __builtin_amdgcn_global_load_lds(
      (const __attribute__((address_space(1))) void*)g,
      (__attribute__((address_space(3))) void*)l, 16, 0, 0);
}

__device__ __forceinline__ float blockReduce128(float v, float* red, int t){
  red[t] = v; __syncthreads();
  #pragma unroll
  for (int off = 64; off > 0; off >>= 1){
    if (t < off) red[t] += red[t+off];
    __syncthreads();
  }
  float r = red[0];
  __syncthreads();
  return r;
}

// ---------------- kernel 0: casts; u and W -> fragment-linear layouts ------
// Frag-linear (MFMA 16x16x32 bf16 operand): for (tile = row>>4, kt = k>>5):
// 1KB block, lane = koct*16 + (row&15), holds Mat[row][kt*32+koct*8 .. +8].
// offset(elems) = (tile*NKT + kt)*512 + koct*128 + (row&15)*8 + (k&7).
__global__ __launch_bounds__(256) void prep_kernel(
    const float4* __restrict__ u4, const float4* __restrict__ win4,
    const float4* __restrict__ wout4,
    bf16_t* __restrict__ uSh, bf16_t* __restrict__ winSh, bf16_t* __restrict__ woutSh,
    float* __restrict__ Asum, float* __restrict__ xraw)
{
  size_t i = (size_t)blockIdx.x*256 + threadIdx.x;
  if (i == 0) Asum[0] = 0.f;
  if (i < ROWS) xraw[i] = 0.f;
  const size_t NU4 = (size_t)ROWS*DMODEL/4;
  const size_t NW4 = (size_t)ZPAD*DMODEL/4;
  const size_t NO4 = (size_t)DMODEL*EDIM/4;
  if (i < NU4){
    float4 v = u4[i];
    size_t e = i*4, row = e>>10, k = e&1023;
    bf16x4 o = { (bf16_t)v.x, (bf16_t)v.y, (bf16_t)v.z, (bf16_t)v.w };
    int mt = (int)(row>>4), rowf = (int)(row&15);
    int kt = (int)(k>>5), koct = (int)((k>>3)&3), ko = (int)(k&7);
    size_t off = (((size_t)mt*32 + kt)<<9) + (koct<<7) + (rowf<<3) + ko;
    *(bf16x4*)&uSh[off] = o;
    return;
  }
  i -= NU4;
  if (i < NW4){
    size_t e = i*4, row = e>>10, k = e&1023;
    bf16x4 o;
    if (row < (size_t)ZDIM){
      float4 v = win4[i];
      o = bf16x4{ (bf16_t)v.x, (bf16_t)v.y, (bf16_t)v.z, (bf16_t)v.w };
    } else {
      o = bf16x4{ (bf16_t)0.f, (bf16_t)0.f, (bf16_t)0.f, (bf16_t)0.f };
    }
    int ntile = (int)(row>>4), colf = (int)(row&15);
    int kt = (int)(k>>5), koct = (int)((k>>3)&3), ko = (int)(k&7);
    size_t off = (((size_t)ntile*32 + kt)<<9) + (koct<<7) + (colf<<3) + ko;
    *(bf16x4*)&winSh[off] = o;
    return;
  }
  i -= NW4;
  if (i < NO4){
    float4 v = wout4[i];
    size_t e = i*4, row = e>>11, k = e&2047;
    bf16x4 o = { (bf16_t)v.x, (bf16_t)v.y, (bf16_t)v.z, (bf16_t)v.w };
    int ntile = (int)(row>>4), colf = (int)(row&15);
    int kt = (int)(k>>5), koct = (int)((k>>3)&3), ko = (int)(k&7);
    size_t off = (((size_t)ntile*64 + kt)<<9) + (koct<<7) + (colf<<3) + ko;
    *(bf16x4*)&woutSh[off] = o;
  }
}

// -------- GEMM-D: ZERO LDS / ZERO barriers — both operands direct VMEM ----
// C = A @ W^T, both frag-linear. 128x256 tile, 4 waves (2Mx2N) free-running,
// per-wave 64x128 (acc[4][8]). Register double-buffer (even/odd steps, static
// indexing). Compiler schedules counted vmcnt; loads issued 32 MFMAs ahead.
// Epilogue (GEMM1): n0<2048 -> silu row-sum atomics into xraw;
//   2048..4095 -> silu -> o_g (row-major stride LDG, GEMM2's A); else o_z.
template<int NKT, int NT, int NXT>
__global__ __launch_bounds__(256, 2) void gemmD_kernel(
    const bf16_t* __restrict__ Ash, const bf16_t* __restrict__ Bsh,
    float* __restrict__ xraw, bf16_t* __restrict__ o_g, float* __restrict__ o_z)
{
  const int tid = threadIdx.x;
  const int wid = tid>>6, lane = tid&63;
  const int wr = wid>>1, wc = wid&1;
  const int lr = lane&15, hi = lane>>4;

  constexpr int MB = ROWS/128;
  constexpr int NWG = NXT*MB;
  const int id = blockIdx.x;
  const int rid = (id & 7)*(NWG/8) + (id>>3);  // bijective (NWG%8==0)
  const int bx = rid % NXT, by = rid / NXT;
  const int m0 = by*128, n0 = bx*256;

  f32x4 acc[4][8] = {};
  constexpr size_t TS = (size_t)NKT*512;       // frag-tile stride (elems)
  const bf16_t* pa = Ash + ((size_t)((m0>>4) + wr*4)*NKT<<9) + lane*8;
  const bf16_t* pb = Bsh + ((size_t)((n0>>4) + wc*8)*NKT<<9) + lane*8;

  bf16x8 aA[4], aB[4], bA[8], bB[8];
  int koff = 0;
  #pragma unroll
  for (int m=0;m<4;++m) aA[m] = *(const bf16x8*)(pa + m*TS + koff);
  #pragma unroll
  for (int n=0;n<8;++n) bA[n] = *(const bf16x8*)(pb + n*TS + koff);
  koff += 512;

  #pragma unroll 1
  for (int t2 = 0; t2 < NT/2; ++t2){
    // ---- even: prefetch t+1 into aB/bB, compute tile t (aA/bA) ----
    #pragma unroll
    for (int m=0;m<4;++m) aB[m] = *(const bf16x8*)(pa + m*TS + koff);
    #pragma unroll
    for (int n=0;n<8;++n) bB[n] = *(const bf16x8*)(pb + n*TS + koff);
    koff += 512;
    #pragma unroll
    for (int m=0;m<4;++m)
      #pragma unroll
      for (int n=0;n<8;++n)
        acc[m][n] = __builtin_amdgcn_mfma_f32_16x16x32_bf16(aA[m], bA[n], acc[m][n], 0,0,0);
    // ---- odd: prefetch t+2 into aA/bA, compute tile t+1 (aB/bB) ----
    const bool pf = (t2 < NT/2 - 1);
    if (pf){
      #pragma unroll
      for (int m=0;m<4;++m) aA[m] = *(const bf16x8*)(pa + m*TS + koff);
      #pragma unroll
      for (int n=0;n<8;++n) bA[n] = *(const bf16x8*)(pb + n*TS + koff);
      koff += 512;
    }
    #pragma unroll
    for (int m=0;m<4;++m)
      #pragma unroll
      for (int n=0;n<8;++n)
        acc[m][n] = __builtin_amdgcn_mfma_f32_16x16x32_bf16(aB[m], bB[n], acc[m][n], 0,0,0);
  }

  // ---- epilogue: row = m0 + wr*64 + m*16 + hi*4 + i; col = n0 + wc*128 + n*16 + lr
  if (n0 < 2048){
    #pragma unroll
    for (int m = 0; m < 4; ++m){
      #pragma unroll
      for (int i = 0; i < 4; ++i){
        float p = 0.f;
        #pragma unroll
        for (int n = 0; n < 8; ++n) p += silu_f(acc[m][n][i]);
        p += __shfl_xor(p, 8); p += __shfl_xor(p, 4);
        p += __shfl_xor(p, 2); p += __shfl_xor(p, 1);
        if (lr == 0){
          int r = m0 + wr*64 + m*16 + (hi<<2) + i;
          atomicAdd(xraw + r, p);
        }
      }
    }
  } else {
    #pragma unroll
    for (int m = 0; m < 4; ++m){
      int rowb = m0 + wr*64 + m*16 + (hi<<2);
      #pragma unroll
      for (int n = 0; n < 8; ++n){
        int col = n0 + wc*128 + n*16 + lr;
        #pragma unroll
        for (int i = 0; i < 4; ++i){
          int r = rowb + i;
          float v = acc[m][n][i];
          if (col < 4096)      o_g[(size_t)r*LDG + (col-2048)] = (bf16_t)silu_f(v);
          else if (col < 4480) o_z[(size_t)r*384 + (col-4096)] = v;
        }
      }
    }
  }
}

// -------- GEMM-V (R12-verified): A via LDS-DMA, B direct VMEM frags -------
// Used for GEMM2 (control). MODE 1: plain scaled stores.
template<int LDA_, int NKT, int NT, int NXT>
__global__ __launch_bounds__(256, 2) void gemmV_kernel(
    const bf16_t* __restrict__ A0, const bf16_t* __restrict__ Bsh,
    const float* __restrict__ scale, float* __restrict__ o_f)
{
  __shared__ __align__(16) bf16_t lds[8192];

  const int tid = threadIdx.x;
  const int wid = tid>>6, lane = tid&63;
  const int wr = wid>>1, wc = wid&1;
  const int lr = lane&15, hi = lane>>4;

  constexpr int MB = ROWS/128;
  constexpr int NWG = NXT*MB;
  const int id = blockIdx.x;
  const int rid = (id & 7)*(NWG/8) + (id>>3);
  const int bx = rid % NXT, by = rid / NXT;
  const int m0 = by*128, n0 = bx*256;

  f32x4 acc[4][8] = {};

  const bf16_t* pA0; const bf16_t* pA1;
  int dA0, dA1;
  {
    int c0 = tid,      r0 = c0>>2, d0 = c0&3, g0 = (d0 - (r0>>1)) & 3;
    int c1 = 256+tid,  r1 = c1>>2, d1 = c1&3, g1 = (d1 - (r1>>1)) & 3;
    pA0 = A0 + (size_t)(m0+r0)*LDA_ + g0*8;
    pA1 = A0 + (size_t)(m0+r1)*LDA_ + g1*8;
    dA0 = c0*8; dA1 = c1*8;
  }
  int aoff[4];
  {
    int R0 = wr*64 + lr;
    int cA = (hi + (R0>>1)) & 3;
    #pragma unroll
    for (int m = 0; m < 4; ++m) aoff[m] = (R0 + 16*m)*32 + cA*8;
  }
  const bf16_t* bB0 = Bsh + (((size_t)((n0>>4) + wc*8)*NKT)<<9) + lane*8;
  int koff = 0;

  bf16x8 bA[8], bB[8], af[4];

  gload_lds16(pA0, &lds[dA0]); pA0 += 32;
  gload_lds16(pA1, &lds[dA1]); pA1 += 32;
  #pragma unroll
  for (int n = 0; n < 8; ++n)
    bA[n] = *(const bf16x8*)(bB0 + (size_t)n*(NKT*512) + koff);
  koff += 512;
  asm volatile("s_waitcnt vmcnt(8)" ::: "memory");
  __builtin_amdgcn_s_barrier();

  #pragma unroll 1
  for (int t2 = 0; t2 < NT/2; ++t2){
    {
      #pragma unroll
      for (int m = 0; m < 4; ++m) af[m] = *(const bf16x8*)&lds[aoff[m]];
      gload_lds16(pA0, &lds[4096 + dA0]); pA0 += 32;
      gload_lds16(pA1, &lds[4096 + dA1]); pA1 += 32;
      #pragma unroll
      for (int n = 0; n < 8; ++n)
        bB[n] = *(const bf16x8*)(bB0 + (size_t)n*(NKT*512) + koff);
      koff += 512;
      #pragma unroll
      for (int m = 0; m < 4; ++m)
        #pragma unroll
        for (int n = 0; n < 8; ++n)
          acc[m][n] = __builtin_amdgcn_mfma_f32_16x16x32_bf16(af[m], bA[n], acc[m][n], 0,0,0);
      asm volatile("s_waitcnt vmcnt(8)" ::: "memory");
      __builtin_amdgcn_s_barrier();
    }
    {
      #pragma unroll
      for (int m = 0; m < 4; ++m) af[m] = *(const bf16x8*)&lds[4096 + aoff[m]];
      const bool pf = (t2 < NT/2 - 1);
      if (pf){
        gload_lds16(pA0, &lds[dA0]); pA0 += 32;
        gload_lds16(pA1, &lds[dA1]); pA1 += 32;
        #pragma unroll
        for (int n = 0; n < 8; ++n)
          bA[n] = *(const bf16x8*)(bB0 + (size_t)n*(NKT*512) + koff);
        koff += 512;
      }
      #pragma unroll
      for (int m = 0; m < 4; ++m)
        #pragma unroll
        for (int n = 0; n < 8; ++n)
          acc[m][n] = __builtin_amdgcn_mfma_f32_16x16x32_bf16(af[m], bB[n], acc[m][n], 0,0,0);
      if (pf) { asm volatile("s_waitcnt vmcnt(8)" ::: "memory"); }
      else    { asm volatile("s_waitcnt vmcnt(0)" ::: "memory"); }
      __builtin_amdgcn_s_barrier();
    }
  }

  #pragma unroll
  for (int m = 0; m < 4; ++m){
    int rowb = m0 + wr*64 + m*16 + (hi<<2);
    #pragma unroll
    for (int i = 0; i < 4; ++i){
      int r = rowb + i;
      float s = scale[r];
      #pragma unroll
      for (int n = 0; n < 8; ++n){
        int col = n0 + wc*128 + n*16 + lr;
        o_f[(size_t)r*DMODEL + col] = acc[m][n][i]*s;
      }
    }
  }
}

// ---------------- kernel 2: per-token fuse (RMS + scalars) ----------------
__global__ __launch_bounds__(128) void fuse_kernel(
    const float* __restrict__ xraw, const float* __restrict__ zs,
    const float* __restrict__ wnB, const float* __restrict__ wnC,
    const float* __restrict__ Bb, const float* __restrict__ Cb,
    const float* __restrict__ dtb, const float* __restrict__ Alog,
    float* __restrict__ Bn, float* __restrict__ Cn, float* __restrict__ dtth,
    float* __restrict__ dts, float* __restrict__ alphas, float* __restrict__ lams,
    float* __restrict__ xbar, float* Asum)
{
  __shared__ float red[128];
  int r = blockIdx.x, t = threadIdx.x;
  const float* zr = zs + (size_t)r*384;
  float bv = zr[t], cv = zr[128+t];
  float b2 = blockReduce128(bv*bv, red, t);
  float c2 = blockReduce128(cv*cv, red, t);
  float rb = rsqrtf(b2*(1.f/128.f) + EPSV);
  float rc = rsqrtf(c2*(1.f/128.f) + EPSV);
  Bn[(size_t)r*128 + t] = bv*rb*wnB[t] + Bb[t];
  Cn[(size_t)r*128 + t] = cv*rc*wnC[t] + Cb[t];

  float dt = softplus_f(zr[256] + dtb[0]);
  if (t < 64) dtth[(size_t)r*64 + t] = dt * zr[258+t];
  if (t == 0){
    float Av  = -softplus_f(zr[257] + Alog[0]);
    float lam = sigmoid_f(zr[322]);
    dts[r]    = dt;
    alphas[r] = expf(dt*Av);
    lams[r]   = lam;
    xbar[r]   = xraw[r] * (1.f/2048.f);
    atomicAdd(Asum, Av);
  }
}

// ---------------- kernel 3a: per-chunk angle sums ----------------
__global__ __launch_bounds__(64) void rope_sum_kernel(
    const float* __restrict__ dtth, float* __restrict__ csum)
{
  int b  = blockIdx.x >> 7;
  int ch = blockIdx.x & 127;
  int d  = threadIdx.x;
  const float* base = dtth + ((size_t)b*LSEQ + (size_t)ch*RCLEN)*64 + d;
  float s = 0.f;
  #pragma unroll
  for (int i = 0; i < RCLEN; ++i) s += base[(size_t)i*64];
  csum[((size_t)b*RCH + ch)*64 + d] = s;
}

// ---------------- kernel 3b: exclusive prefix over chunks (in place) -------
__global__ __launch_bounds__(64) void rope_prefix_kernel(float* __restrict__ csum)
{
  int b = blockIdx.x, d = threadIdx.x;
  float s = 0.f;
  for (int c = 0; c < RCH; ++c){
    size_t idx = ((size_t)b*RCH + c)*64 + d;
    float v = csum[idx]; csum[idx] = s; s += v;
  }
}

// ------- kernel 3c+4a merged: rope (in-register) + chunk-local scan -------
__global__ __launch_bounds__(64) void rope_scan_kernel(
    const float* __restrict__ dtth, const float* __restrict__ csum,
    const float* __restrict__ dts, const float* __restrict__ alphas,
    const float* __restrict__ lams, const float* __restrict__ xbar,
    const float* __restrict__ Asum,
    const float* __restrict__ Bn, float* __restrict__ Cn,
    float* __restrict__ ylocal, float* __restrict__ Pfix,
    float* __restrict__ Sfin, float* __restrict__ Dch)
{
  int b  = blockIdx.x >> 7;
  int ch = blockIdx.x & 127;
  int d  = threadIdx.x;
  float Abar = Asum[0] * (1.f/(float)ROWS);
  float ca = csum[((size_t)b*RCH + ch)*64 + d];
  float s1 = 0.f, s2 = 0.f, P = 1.f;
  int l0 = ch*SCLEN;
  #pragma unroll
  for (int i = 0; i < SCLEN; ++i){
    int l = l0 + i;
    size_t r = (size_t)b*LSEQ + l;
    ca += dtth[r*64 + d];
    float sn, cs;
    sincosf(ca, &sn, &cs);
    size_t ro = r*128;
    float b1 = Bn[ro+d], b2v = Bn[ro+64+d];
    float rb1 = b1*cs - b2v*sn;
    float rb2 = b1*sn + b2v*cs;
    float c1 = Cn[ro+d], c2v = Cn[ro+64+d];
    float rc1 = c1*cs - c2v*sn;
    float rc2 = c1*sn + c2v*cs;
    Cn[ro+d]    = rc1;
    Cn[ro+64+d] = rc2;

    float dt = dts[r], lam = lams[r], al = alphas[r], xb = xbar[r];
    float xp = (l > 0) ? xbar[r-1] : 0.f;
    float um = lam*xb + (1.f-lam)*al*xp;
    float dA = expf(dt*Abar);
    float coef = dt*um;
    s1 = dA*s1 + coef*rb1;
    s2 = dA*s2 + coef*rb2;
    P *= dA;
    float p = s1*rc1 + s2*rc2;
    #pragma unroll
    for (int off = 32; off > 0; off >>= 1) p += __shfl_down(p, off);
    if (d == 0){ ylocal[r] = p; Pfix[r] = P; }
  }
  size_t so = ((size_t)b*SCHUNK + ch)*128;
  Sfin[so + d]      = s1;
  Sfin[so + 64 + d] = s2;
  if (d == 0) Dch[b*SCHUNK + ch] = P;
}

// ---------------- kernel 4b: inter-chunk carry ----------------
__global__ __launch_bounds__(128) void scan_carry_kernel(
    const float* __restrict__ Sfin, const float* __restrict__ Dch,
    float* __restrict__ Sin)
{
  int b = blockIdx.x;
  int n = threadIdx.x;
  float s = 0.f;
  for (int c = 0; c < SCHUNK; ++c){
    size_t so = ((size_t)b*SCHUNK + c)*128;
    Sin[so + n] = s;
    s = Dch[b*SCHUNK + c]*s + Sfin[so + n];
  }
}

// ---------------- kernel 4c: fixup ----------------
__global__ __launch_bounds__(256) void scan_fix_kernel(
    const float* __restrict__ Cn, const float* __restrict__ Sin,
    const float* __restrict__ ylocal, const float* __restrict__ Pfix,
    float* __restrict__ outsv)
{
  int r = blockIdx.x*4 + (threadIdx.x>>6);
  int n = threadIdx.x & 63;
  int b  = r / LSEQ;
  int ch = (r % LSEQ) / SCLEN;
  const float* si = Sin + ((size_t)b*SCHUNK + ch)*128;
  size_t ro = (size_t)r*128;
  float p = Cn[ro+n]*si[n] + Cn[ro+64+n]*si[64+n];
  #pragma unroll
  for (int off = 32; off > 0; off >>= 1) p += __shfl_down(p, off);
  if (n == 0) outsv[r] = ylocal[r] + Pfix[r]*p;
}

// ---------------- launch ----------------
extern "C" void kernel_launch(void* const* d_in, const int* in_sizes, int n_in,
                              void* d_out, int out_size, void* d_ws, size_t ws_size,
                              hipStream_t stream)
{
  const float* u    = (const float*)d_in[0];
  const float* W_in = (const float*)d_in[1];
  const float* wnB  = (const float*)d_in[2];
  const float* wnC  = (const float*)d_in[3];
  const float* Bb   = (const float*)d_in[4];
  const float* Cb   = (const float*)d_in[5];
  const float* dtb  = (const float*)d_in[6];
  const float* Alog = (const float*)d_in[7];
  const float* Wout = (const float*)d_in[8];
  float* out = (float*)d_out;
  char* ws = (char*)d_ws;

  constexpr size_t OFF_ASUM = 0;
  constexpr size_t OFF_UBF  = 256;
  constexpr size_t SZ_UBF   = (size_t)ROWS*LDU*2;
  constexpr size_t OFF_WIN  = OFF_UBF + SZ_UBF;
  constexpr size_t SZ_WIN   = (size_t)ZPAD*LDU*2;
  constexpr size_t OFF_WOUT = OFF_WIN + SZ_WIN;
  constexpr size_t SZ_WOUT  = (size_t)DMODEL*LDG*2;
  constexpr size_t OFF_G    = OFF_WOUT + SZ_WOUT;
  constexpr size_t SZ_G     = (size_t)ROWS*LDG*2;
  constexpr size_t OFF_ZS   = OFF_G + SZ_G;
  constexpr size_t SZ_ZS    = (size_t)ROWS*384*4;
  constexpr size_t OFF_BN   = OFF_ZS + SZ_ZS;
  constexpr size_t SZ_BN    = (size_t)ROWS*128*4;
  constexpr size_t OFF_CN   = OFF_BN + SZ_BN;
  constexpr size_t OFF_DTTH = OFF_CN + SZ_BN;
  constexpr size_t SZ_DTTH  = (size_t)ROWS*64*4;
  constexpr size_t OFF_XRAW = OFF_DTTH + SZ_DTTH;
  constexpr size_t OFF_DT   = OFF_XRAW + (size_t)ROWS*4;
  constexpr size_t OFF_AL   = OFF_DT  + (size_t)ROWS*4;
  constexpr size_t OFF_LAM  = OFF_AL  + (size_t)ROWS*4;
  constexpr size_t OFF_XB   = OFF_LAM + (size_t)ROWS*4;
  constexpr size_t OFF_OUTS = OFF_XB  + (size_t)ROWS*4;
  constexpr size_t OFF_YLOC = OFF_OUTS + (size_t)ROWS*4;
  constexpr size_t OFF_PFIX = OFF_YLOC + (size_t)ROWS*4;
  constexpr size_t OFF_SFIN = OFF_PFIX + (size_t)ROWS*4;
  constexpr size_t SZ_SFIN  = (size_t)B_SZ*SCHUNK*128*4;
  constexpr size_t OFF_DCH  = OFF_SFIN + SZ_SFIN;
  constexpr size_t OFF_SIN  = OFF_DCH + (size_t)B_SZ*SCHUNK*4;
  constexpr size_t OFF_CSUM = OFF_SIN + SZ_SFIN;

  float*  Asum   = (float*) (ws + OFF_ASUM);
  bf16_t* uSh    = (bf16_t*)(ws + OFF_UBF);
  bf16_t* winSh  = (bf16_t*)(ws + OFF_WIN);
  bf16_t* woutSh = (bf16_t*)(ws + OFF_WOUT);
  bf16_t* gbuf   = (bf16_t*)(ws + OFF_G);
  float*  zsb    = (float*) (ws + OFF_ZS);
  float*  Bn     = (float*) (ws + OFF_BN);
  float*  Cn     = (float*) (ws + OFF_CN);
  float*  dtth   = (float*) (ws + OFF_DTTH);
  float*  xraw   = (float*) (ws + OFF_XRAW);
  float*  dts    = (float*) (ws + OFF_DT);
  float*  alphas = (float*) (ws + OFF_AL);
  float*  lams   = (float*) (ws + OFF_LAM);
  float*  xbar   = (float*) (ws + OFF_XB);
  float*  outsv  = (float*) (ws + OFF_OUTS);
  float*  ylocal = (float*) (ws + OFF_YLOC);
  float*  Pfix   = (float*) (ws + OFF_PFIX);
  float*  Sfin   = (float*) (ws + OFF_SFIN);
  float*  Dch    = (float*) (ws + OFF_DCH);
  float*  Sin    = (float*) (ws + OFF_SIN);
  float*  csum   = (float*) (ws + OFF_CSUM);

  {
    size_t total4 = ((size_t)ROWS*DMODEL + (size_t)ZPAD*DMODEL + (size_t)DMODEL*EDIM)/4;
    int blocks = (int)((total4 + 255)/256);
    prep_kernel<<<blocks, 256, 0, stream>>>(
        (const float4*)u, (const float4*)W_in, (const float4*)Wout,
        uSh, winSh, woutSh, Asum, xraw);
  }

  // GEMM1: barrier-free pure-VMEM, 128x256 tiles, 1152 blocks.
  gemmD_kernel<32, 32, ZPAD/256>
      <<<(ZPAD/256)*(ROWS/128), 256, 0, stream>>>(
      uSh, winSh, xraw, gbuf, zsb);
  fuse_kernel<<<ROWS, 128, 0, stream>>>(xraw, zsb, wnB, wnC, Bb, Cb, dtb, Alog,
                                        Bn, Cn, dtth, dts, alphas, lams, xbar, Asum);
  rope_sum_kernel<<<B_SZ*RCH, 64, 0, stream>>>(dtth, csum);
  rope_prefix_kernel<<<B_SZ, 64, 0, stream>>>(csum);
  rope_scan_kernel<<<B_SZ*RCH, 64, 0, stream>>>(dtth, csum, dts, alphas, lams,
                                                xbar, Asum, Bn, Cn,
                                                ylocal, Pfix, Sfin, Dch);
  scan_carry_kernel<<<B_SZ, 128, 0, stream>>>(Sfin, Dch, Sin);
  scan_fix_kernel<<<ROWS/4, 256, 0, stream>>>(Cn, Sin, ylocal, Pfix, outsv);
  // GEMM2: gemmV control (K=2048, NT=64), plain scaled stores. 256 blocks.
  gemmV_kernel<LDG, 64, 64, DMODEL/256>
      <<<(DMODEL/256)*(ROWS/128), 256, 0, stream>>>(
      gbuf, woutSh, outsv, out);
}